// Round 6
// baseline (270.501 us; speedup 1.0000x reference)
//
#include <hip/hip_runtime.h>
#include <hip/hip_bf16.h>
#include <stdint.h>

typedef __bf16 bf16;
typedef __bf16 bf16x4 __attribute__((ext_vector_type(4)));
typedef __bf16 bf16x8 __attribute__((ext_vector_type(8)));
typedef float f32x4 __attribute__((ext_vector_type(4)));

#define GLOBAL_AS __attribute__((address_space(1)))
#define LDS_AS __attribute__((address_space(3)))

__device__ __forceinline__ void g2lds16(const bf16* g, bf16* l) {
  // async global->LDS DMA, 16 B/lane; LDS dest = wave-uniform base + lane*16
  __builtin_amdgcn_global_load_lds((const GLOBAL_AS void*)g, (LDS_AS void*)l, 16, 0, 0);
}

// ---------------------------------------------------------------------------
// Kernel 1: pure streaming RMSNorm (F.normalize * sqrt(1024) * gamma).
// ---------------------------------------------------------------------------
__global__ __launch_bounds__(256) void rmsnorm_kernel(
    const float* __restrict__ x, const float* __restrict__ gamma,
    bf16* __restrict__ xn) {
  __shared__ float wss[4];
  const int t = threadIdx.x;
  const size_t row = blockIdx.x;
  const float* xr = x + row * 1024;

  float4 xv = *(const float4*)&xr[t * 4];
  float v[4] = {xv.x, xv.y, xv.z, xv.w};
  float ss = v[0]*v[0] + v[1]*v[1] + v[2]*v[2] + v[3]*v[3];
#pragma unroll
  for (int mm = 1; mm < 64; mm <<= 1) ss += __shfl_xor(ss, mm);
  if ((t & 63) == 0) wss[t >> 6] = ss;
  __syncthreads();
  ss = wss[0] + wss[1] + wss[2] + wss[3];
  float inv = 32.0f / sqrtf(fmaxf(ss, 1e-24f));  // sqrt(1024)=32

  float4 gv = *(const float4*)&gamma[t * 4];
  float gvv[4] = {gv.x, gv.y, gv.z, gv.w};
  bf16x4 outv;
#pragma unroll
  for (int i = 0; i < 4; ++i) outv[i] = (bf16)(v[i] * inv * gvv[i]);
  *(bf16x4*)&xn[row * 1024 + t * 4] = outv;
}

// ---------------------------------------------------------------------------
// Kernel 2: fp32 -> bf16 transpose (for B^T GEMM operand), 32x32 tiles
// ---------------------------------------------------------------------------
__global__ void transpose_f32_bf16(const float* __restrict__ in, bf16* __restrict__ out,
                                   int R, int C) {
  __shared__ bf16 tile[32][33];
  const int tx = threadIdx.x, ty = threadIdx.y;  // 32 x 8
  const int c0 = blockIdx.x * 32, r0 = blockIdx.y * 32;
#pragma unroll
  for (int i = 0; i < 32; i += 8)
    tile[ty + i][tx] = (bf16)in[(size_t)(r0 + ty + i) * C + c0 + tx];
  __syncthreads();
#pragma unroll
  for (int i = 0; i < 32; i += 8)
    out[(size_t)(c0 + ty + i) * R + r0 + tx] = tile[tx][ty + i];
}

// Wg [1024,16] -> rows 3072..3087 of BtAug [3200,1024]. Tiny (16K elements).
__global__ __launch_bounds__(256) void wg_transpose(const float* __restrict__ Wg,
                                                    bf16* __restrict__ BtAug) {
  int idx = blockIdx.x * 256 + threadIdx.x;   // [0, 16384)
  int n = idx >> 10, k = idx & 1023;
  BtAug[(size_t)(3072 + n) * 1024 + k] = (bf16)Wg[(size_t)k * 16 + n];
}

// ---------------------------------------------------------------------------
// Kernel 3a: MFMA bf16 GEMM, 128x128 tile, BK=64, 2-barrier structure.
// Kept for the output GEMM (N=1024: 512-block grid balances the GPU).
// ---------------------------------------------------------------------------
template <typename OutT>
__global__ __launch_bounds__(256) void gemm_bt_128(
    const bf16* __restrict__ A, const bf16* __restrict__ Bt,
    OutT* __restrict__ C, int M, int N, int K) {
  __shared__ bf16 lA[128 * 64];
  __shared__ bf16 lB[128 * 64];
  const int t = threadIdx.x;
  const int w = t >> 6, lane = t & 63;
  const int col0 = lane & 15, quad = lane >> 4;
  const int m0 = blockIdx.y * 128, n0 = blockIdx.x * 128;
  const int wr = (w >> 1) * 64, wc = (w & 1) * 64;

  const int lrow = t >> 3;                          // 0..31 (includes w*8)
  const int sswz = (((t & 7) ^ (lrow & 7)) << 3);   // swizzled src k-offset

  f32x4 acc[4][4] = {};

  for (int k0 = 0; k0 < K; k0 += 64) {
    __syncthreads();  // previous iteration's LDS reads done
#pragma unroll
    for (int c = 0; c < 4; ++c) {
      g2lds16(A  + (size_t)(m0 + c * 32 + lrow) * K + k0 + sswz, &lA[c * 2048 + w * 512]);
      g2lds16(Bt + (size_t)(n0 + c * 32 + lrow) * K + k0 + sswz, &lB[c * 2048 + w * 512]);
    }
    __syncthreads();  // drains vmcnt(0): staged tiles visible

#pragma unroll
    for (int kh = 0; kh < 2; ++kh) {
      bf16x8 af[4], bfr[4];
#pragma unroll
      for (int i = 0; i < 4; ++i) {
        int row = wr + i * 16 + col0;
        af[i] = *(const bf16x8*)&lA[row * 64 + (((kh * 4 + quad) ^ (row & 7)) << 3)];
      }
#pragma unroll
      for (int j = 0; j < 4; ++j) {
        int row = wc + j * 16 + col0;
        bfr[j] = *(const bf16x8*)&lB[row * 64 + (((kh * 4 + quad) ^ (row & 7)) << 3)];
      }
#pragma unroll
      for (int i = 0; i < 4; ++i)
#pragma unroll
        for (int j = 0; j < 4; ++j)
          acc[i][j] = __builtin_amdgcn_mfma_f32_16x16x32_bf16(af[i], bfr[j], acc[i][j], 0, 0, 0);
    }
  }

#pragma unroll
  for (int i = 0; i < 4; ++i)
#pragma unroll
    for (int j = 0; j < 4; ++j)
#pragma unroll
      for (int r = 0; r < 4; ++r) {
        int row = m0 + wr + i * 16 + quad * 4 + r;
        int col = n0 + wc + j * 16 + col0;
        C[(size_t)row * N + col] = (OutT)acc[i][j][r];
      }
}

// ---------------------------------------------------------------------------
// Kernel 3b v6: 256x256 GEMM, A LDS-staged, B DIRECT from L2 into registers.
//
// R5 model: with A+B both DMA-staged, staged bytes = 128 KB/tile; at L2->CU
// service ~33-40 B/cyc that is 3300-3900 cyc/tile > MFMA 2483 -> the DMA
// path paces the kernel (m201's measured 3963 cyc/tile = same wall). Fix:
// B fragments are contiguous 16B chunks of Bt (row-major, K contiguous) and
// B is 6.5 MB of L2/L3-hot weights -> read bv[4][2] directly into regs once
// per tile. Staged DMA drops to A-only 64 KB/tile (~1900 cyc) -> MFMA pipe
// becomes binding. LDS halves to 64 KB (A dbuf only); B ds_reads vanish.
//
// Tile body (ONE barrier + ONE vmcnt per tile; waves decouple inside):
//   s_waitcnt vmcnt(0)  // drains DMA(T) (issued 1 tile ago; B(T-1) already
//                       // consumed by phase-3 MFMA waits -> only DMAs left)
//   s_barrier           // A[T&1] visible to all; WAR: each wave's tile-T-1
//                       // ds_reads were lgkm-drained before its last MFMA,
//                       // hence before it reached this barrier
//   load bv[4][2] (8x global b128, compiler-counted waits)
//   sched_barrier(0)    // pin bv loads BEFORE the DMAs: vmcnt is FIFO, so
//                       // compiler bv-waits never force-drain fresh DMAs
//   issue DMA(T+1) into other buffer (4 calls)
//   4 x { 4 af ds_read_b128 ; 16 MFMA }  // plain code: compiler emits
//                       // fine-grained lgkmcnt + interleaves with MFMA
// Swizzle: A LDS[row][ck]=G[row][ck^(row&7)] via pre-swizzled source; reads
// XOR the same involution (0-conflict, measured). B direct addressing equals
// the old staged+deswizzled value: Bt[row][k0 + (ks*4+quad)*8].
// Partial col tile (N=3200): B row clamp to N-1 (zeroed pad row), stores
// guarded col<N.
// ---------------------------------------------------------------------------
template <typename OutT>
__global__ __launch_bounds__(512, 2) void gemm_bt_256(
    const bf16* __restrict__ A, const bf16* __restrict__ Bt,
    OutT* __restrict__ C, int M, int N, int K) {
  __shared__ bf16 lA[2][256 * 64];   // 64 KB total

  const int t = threadIdx.x;
  const int w = t >> 6, lane = t & 63;
  const int wm = w >> 2, wn = w & 3;
  const int col0 = lane & 15, quad = lane >> 4;
  const int sswz = (((t & 7) ^ ((t >> 3) & 7)) << 3);  // pre-swizzled src chunk

  // XCD-aware bijective swizzle (requires nwg % 8 == 0; 416 is)
  int nwg = gridDim.x * gridDim.y;
  int bid = blockIdx.y * gridDim.x + blockIdx.x;
  int swz = bid;
  if ((nwg & 7) == 0) swz = (bid & 7) * (nwg >> 3) + (bid >> 3);
  const int n0 = (swz % gridDim.x) * 256;
  const int m0 = (swz / gridDim.x) * 256;

  const bf16* Abase = A + (size_t)m0 * (size_t)K;

  // quarter c = 64 rows; 512 threads x 16B = exactly one quarter per call
  auto stageA = [&](int ks, int c, bf16* dstA) {
    int row = c * 64 + (t >> 3);
    g2lds16(Abase + (size_t)row * K + ks + sswz, dstA + c * 4096 + w * 512);
  };

  // B row base pointers (per-thread, fixed): row = n0 + wn*64 + nj*16 + col0
  const bf16* brow[4];
#pragma unroll
  for (int nj = 0; nj < 4; ++nj) {
    int gr = n0 + wn * 64 + nj * 16 + col0;
    gr = (gr < N) ? gr : (N - 1);   // clamp: partial tile reads zero-pad row
    brow[nj] = Bt + (size_t)gr * (size_t)K + quad * 8;
  }

  f32x4 acc[4][2][4] = {};   // [band q][m2][nj]
  const int NT = K >> 6;     // K-tiles (16 for K=1024)

  // prologue: DMA tile 0 (one-time ~full-latency wait at T=0's vmcnt)
  stageA(0, 0, lA[0]); stageA(0, 1, lA[0]); stageA(0, 2, lA[0]); stageA(0, 3, lA[0]);

  for (int T = 0; T < NT; ++T) {
    bf16* cur = lA[T & 1];
    bf16* nxt = lA[(T + 1) & 1];
    const int k0 = T << 6;

    asm volatile("s_waitcnt vmcnt(0)" ::: "memory");  // DMA(T) landed
    asm volatile("s_barrier" ::: "memory");           // A[cur] readable

    // B(T) direct loads into regs (held across the tile)
    bf16x8 bv[4][2];
#pragma unroll
    for (int nj = 0; nj < 4; ++nj)
#pragma unroll
      for (int ks = 0; ks < 2; ++ks)
        bv[nj][ks] = *(const bf16x8*)(brow[nj] + k0 + ks * 32);
    __builtin_amdgcn_sched_barrier(0);  // bv loads stay OLDER than the DMAs

    // DMA(T+1) into the other buffer (WAR-safe: see barrier note above)
    if (T + 1 < NT) {
      const int kn = (T + 1) << 6;
      stageA(kn, 0, nxt); stageA(kn, 1, nxt); stageA(kn, 2, nxt); stageA(kn, 3, nxt);
    }

    // 4 bands: {4 af ds_reads; 16 MFMA}; compiler-interleaved lgkmcnt
#pragma unroll
    for (int q = 0; q < 4; ++q) {
      bf16x8 af[2][2];
#pragma unroll
      for (int m2 = 0; m2 < 2; ++m2) {
        int ar = q * 64 + wm * 32 + m2 * 16 + col0;
#pragma unroll
        for (int ks = 0; ks < 2; ++ks)
          af[m2][ks] = *(const bf16x8*)&cur[ar * 64 + (((ks * 4 + quad) ^ (ar & 7)) << 3)];
      }
      __builtin_amdgcn_s_setprio(1);
#pragma unroll
      for (int ks = 0; ks < 2; ++ks)
#pragma unroll
        for (int m2 = 0; m2 < 2; ++m2)
#pragma unroll
          for (int nj = 0; nj < 4; ++nj)
            acc[q][m2][nj] = __builtin_amdgcn_mfma_f32_16x16x32_bf16(
                af[m2][ks], bv[nj][ks], acc[q][m2][nj], 0, 0, 0);
      __builtin_amdgcn_s_setprio(0);
    }
  }
  asm volatile("s_waitcnt vmcnt(0)" ::: "memory");  // (nothing left; hygiene)

  // epilogue: band q rows = m0 + q*64 + wm*32 + m2*16 + quad*4 + r
#pragma unroll
  for (int q = 0; q < 4; ++q)
#pragma unroll
    for (int m2 = 0; m2 < 2; ++m2)
#pragma unroll
      for (int nj = 0; nj < 4; ++nj) {
        int col = n0 + wn * 64 + nj * 16 + col0;
        if (col < N) {
          size_t base = (size_t)(m0 + q * 64 + wm * 32 + m2 * 16 + quad * 4) * N + col;
#pragma unroll
          for (int r = 0; r < 4; ++r)
            C[base + (size_t)r * N] = (OutT)acc[q][m2][nj][r];
        }
      }
}

// ---------------------------------------------------------------------------
// Kernel 4 v5: sliding-window attention, swapped-operand form (unchanged).
// ---------------------------------------------------------------------------
#define NEG_BIG -1e30f
__global__ __launch_bounds__(256, 4) void attn_kernel(
    const bf16* __restrict__ qkv, const float* __restrict__ bg,
    bf16* __restrict__ attnO) {
  __shared__ bf16 lKV[320 * 64];   // 40 KB: K[320][64] ph1, Vt[64][320] ph2

  const int t = threadIdx.x;
  const int lane = t & 63;
  const int w = t >> 6;
  const int col0 = lane & 15, quad = lane >> 4;

  const int bid = blockIdx.x;
  const int blk = ((bid & 7) << 8) | (bid >> 3);   // XCD-chunked (2048 % 8 == 0)
  const int g = blk & 63;
  const int h = (blk >> 6) & 15;
  const int bb = blk >> 10;
  const int qs = g * 64;

  const size_t rs = 3200;
  const bf16* qbase = qkv + ((size_t)bb * 4096) * rs + h * 64;

  // ---- stage K[320][64] via async DMA (chunk-swizzled via source)
  {
    const int lr = t >> 3;                          // 0..31 (includes w*8)
    const int sswz = ((t & 7) ^ (lr & 7)) << 3;
#pragma unroll
    for (int c = 0; c < 10; ++c) {
      int j = qs - 256 + c * 32 + lr;
      j = (j < 0) ? 0 : j;                          // clamp: masked later
      g2lds16(qbase + 1024 + (size_t)j * rs + sswz, &lKV[c * 2048 + w * 512]);
    }
  }
  __builtin_amdgcn_sched_barrier(0);
  // ---- Q B-operand frags + gate logit direct from global (no LDS)
  const int ql = w * 16 + col0;                     // local query index
  const int srow = qs + ql;
  const bf16x8 bq0 = *(const bf16x8*)(qbase + (size_t)srow * rs + quad * 8);
  const bf16x8 bq1 = *(const bf16x8*)(qbase + (size_t)srow * rs + 32 + quad * 8);
  const float logit = (float)qkv[((size_t)bb * 4096 + srow) * rs + 3072 + h];
  asm volatile("s_waitcnt vmcnt(3)" ::: "memory");  // the 10 K DMAs done
  asm volatile("s_barrier" ::: "memory");

  // ---- QK^T swapped: z[kt] rows k = kt*16+quad*4+r, col q = col0
  f32x4 z[20];
#pragma unroll
  for (int kt = 0; kt < 20; ++kt) {
    const int kr = kt * 16 + col0;
    bf16x8 a0 = *(const bf16x8*)&lKV[kr * 64 + ((quad ^ (kr & 7)) << 3)];
    bf16x8 a1 = *(const bf16x8*)&lKV[kr * 64 + (((4 + quad) ^ (kr & 7)) << 3)];
    f32x4 zz = {};
    zz = __builtin_amdgcn_mfma_f32_16x16x32_bf16(a0, bq0, zz, 0, 0, 0);
    zz = __builtin_amdgcn_mfma_f32_16x16x32_bf16(a1, bq1, zz, 0, 0, 0);
    z[kt] = zz;
  }
  asm volatile("s_barrier" ::: "memory");           // all waves done reading K

  // ---- V -> Vt[64][320] overlay (key-major lanes, 2-way-free chunk swizzle)
  {
    const int jl = t & 31, dg = t >> 5;
#pragma unroll
    for (int cc = 0; cc < 10; ++cc) {
      int j = qs - 256 + cc * 32 + jl;
      j = (j < 0) ? 0 : j;                          // finite garbage; P=0 there
      bf16 tmp[8];
      *(uint4*)tmp = *(const uint4*)(qbase + 2048 + (size_t)j * rs + dg * 8);
      const int ck = cc * 4 + (jl >> 3);
      const int wi = jl & 7;
#pragma unroll
      for (int d2 = 0; d2 < 8; ++d2) {
        const int d = dg * 8 + d2;
        lKV[d * 320 + ((ck ^ (d & 7)) << 3) + wi] = tmp[d2];
      }
    }
  }

  // ---- softmax: lane owns 80 scores of ONE query; 2 shfl rounds per reduce
  float m = NEG_BIG;
#pragma unroll
  for (int kt = 0; kt < 20; ++kt)
#pragma unroll
    for (int r = 0; r < 4; ++r) {
      const int c = kt * 16 + quad * 4 + r;
      const bool valid = (c >= ql) && (c <= ql + 256) && (qs - 256 + c >= 0);
      const float sv = valid ? z[kt][r] * 0.125f : NEG_BIG;  // 1/sqrt(64)
      z[kt][r] = sv;
      m = fmaxf(m, sv);
    }
  m = fmaxf(m, __shfl_xor(m, 16));
  m = fmaxf(m, __shfl_xor(m, 32));
  float l = 0.f;
#pragma unroll
  for (int kt = 0; kt < 20; ++kt)
#pragma unroll
    for (int r = 0; r < 4; ++r) {
      const float p = __expf(z[kt][r] - m);
      z[kt][r] = p;
      l += p;
    }
  l += __shfl_xor(l, 16);
  l += __shfl_xor(l, 32);

  __syncthreads();                                  // Vt visible

  // ---- PV swapped: o[n] = O^T d-band; P transposed in-register.
  f32x4 o[4] = {};
  const int sl0 = col0 + ((quad & 1) << 5);
  const bool hi = quad >= 2;
#pragma unroll
  for (int kc = 0; kc < 10; ++kc) {
    uint32_t Pl0, Pl1, Ph0, Ph1;
    asm("v_cvt_pk_bf16_f32 %0, %1, %2" : "=v"(Pl0) : "v"(z[2*kc][0]),   "v"(z[2*kc][1]));
    asm("v_cvt_pk_bf16_f32 %0, %1, %2" : "=v"(Pl1) : "v"(z[2*kc][2]),   "v"(z[2*kc][3]));
    asm("v_cvt_pk_bf16_f32 %0, %1, %2" : "=v"(Ph0) : "v"(z[2*kc+1][0]), "v"(z[2*kc+1][1]));
    asm("v_cvt_pk_bf16_f32 %0, %1, %2" : "=v"(Ph1) : "v"(z[2*kc+1][2]), "v"(z[2*kc+1][3]));
    uint32_t w0l = __shfl((int)Pl0, sl0),      w0h = __shfl((int)Ph0, sl0);
    uint32_t w1l = __shfl((int)Pl1, sl0),      w1h = __shfl((int)Ph1, sl0);
    uint32_t w2l = __shfl((int)Pl0, sl0 + 16), w2h = __shfl((int)Ph0, sl0 + 16);
    uint32_t w3l = __shfl((int)Pl1, sl0 + 16), w3h = __shfl((int)Ph1, sl0 + 16);
    union { uint32_t u[4]; bf16x8 v; } pu;
    pu.u[0] = hi ? w0h : w0l;
    pu.u[1] = hi ? w1h : w1l;
    pu.u[2] = hi ? w2h : w2l;
    pu.u[3] = hi ? w3h : w3l;
#pragma unroll
    for (int n = 0; n < 4; ++n) {
      const int d = n * 16 + col0;
      bf16x8 av = *(const bf16x8*)&lKV[d * 320 + (((kc * 4 + quad) ^ (d & 7)) << 3)];
      o[n] = __builtin_amdgcn_mfma_f32_16x16x32_bf16(av, pu.v, o[n], 0, 0, 0);
    }
  }

  // ---- epilogue: one query per lane; o rows are d = n*16+quad*4+r
  const float gate = 1.f / (1.f + __expf(-(logit + bg[h])));
  const float scale = gate / l;
  bf16* obase = attnO + ((size_t)bb * 4096 + srow) * 1024 + h * 64;
#pragma unroll
  for (int n = 0; n < 4; ++n) {
    bf16x4 ov;
#pragma unroll
    for (int r = 0; r < 4; ++r) ov[r] = (bf16)(o[n][r] * scale);
    *(bf16x4*)&obase[n * 16 + quad * 4] = ov;
  }
}

// ---------------------------------------------------------------------------
extern "C" void kernel_launch(void* const* d_in, const int* in_sizes, int n_in,
                              void* d_out, int out_size, void* d_ws, size_t ws_size,
                              hipStream_t stream) {
  const float *x = nullptr, *gamma = nullptr, *Wqkv = nullptr,
              *Wg = nullptr, *bg = nullptr, *Wout = nullptr;
  for (int i = 0; i < n_in; ++i) {
    switch (in_sizes[i]) {
      case 8388608: x     = (const float*)d_in[i]; break;
      case 1024:    gamma = (const float*)d_in[i]; break;
      case 3145728: Wqkv  = (const float*)d_in[i]; break;
      case 16384:   Wg    = (const float*)d_in[i]; break;
      case 16:      bg    = (const float*)d_in[i]; break;
      case 1048576: Wout  = (const float*)d_in[i]; break;
    }
  }
  float* out = (float*)d_out;  // fp32 output

  // BtAug = [WqkvT (3072 rows); WgT (16 rows); zero pad (112 rows)] x 1024
  char* ws = (char*)d_ws;
  bf16* qkv   = (bf16*)ws;  ws += (size_t)8192 * 3200 * 2;   // 52.4 MB (incl. gate logits)
  bf16* xn    = (bf16*)ws;                                    // 16 MB, dead after QKV GEMM
  bf16* attnO = (bf16*)ws;  ws += (size_t)8192 * 1024 * 2;   // aliases xn (stream-ordered)
  bf16* BtAug = (bf16*)ws;  ws += (size_t)3200 * 1024 * 2;   // 6.55 MB
  bf16* WoutT = (bf16*)ws;  ws += (size_t)1024 * 1024 * 2;   // total ~77.9 MB

  // zero the 112 pad rows of BtAug (re-poisoned to 0xAA before every call)
  hipMemsetAsync(BtAug + (size_t)3088 * 1024, 0, (size_t)112 * 1024 * 2, stream);

  rmsnorm_kernel<<<8192, 256, 0, stream>>>(x, gamma, xn);
  transpose_f32_bf16<<<dim3(3072 / 32, 1024 / 32), dim3(32, 8), 0, stream>>>(Wqkv, BtAug, 1024, 3072);
  wg_transpose<<<64, 256, 0, stream>>>(Wg, BtAug);
  transpose_f32_bf16<<<dim3(1024 / 32, 1024 / 32), dim3(32, 8), 0, stream>>>(Wout, WoutT, 1024, 1024);
  // QKV GEMM: 256^2 v6 (A staged, B direct), grid 13x32 = 416
  gemm_bt_256<bf16><<<dim3(13, 32), 512, 0, stream>>>(xn, BtAug, qkv, 8192, 3200, 1024);
  attn_kernel<<<2048, 256, 0, stream>>>(qkv, bg, attnO);
  gemm_bt_128<float><<<dim3(1024 / 128, 8192 / 128), 256, 0, stream>>>(attnO, WoutT, out, 8192, 1024, 1024);
}

// Round 7
// 232.490 us; speedup vs baseline: 1.1635x; 1.1635x over previous
//
#include <hip/hip_runtime.h>
#include <hip/hip_bf16.h>
#include <stdint.h>

typedef __bf16 bf16;
typedef __bf16 bf16x4 __attribute__((ext_vector_type(4)));
typedef __bf16 bf16x8 __attribute__((ext_vector_type(8)));
typedef float f32x4 __attribute__((ext_vector_type(4)));

#define GLOBAL_AS __attribute__((address_space(1)))
#define LDS_AS __attribute__((address_space(3)))

__device__ __forceinline__ void g2lds16(const bf16* g, bf16* l) {
  // async global->LDS DMA, 16 B/lane; LDS dest = wave-uniform base + lane*16
  __builtin_amdgcn_global_load_lds((const GLOBAL_AS void*)g, (LDS_AS void*)l, 16, 0, 0);
}

// ---------------------------------------------------------------------------
// Kernel 1: pure streaming RMSNorm (F.normalize * sqrt(1024) * gamma).
// ---------------------------------------------------------------------------
__global__ __launch_bounds__(256) void rmsnorm_kernel(
    const float* __restrict__ x, const float* __restrict__ gamma,
    bf16* __restrict__ xn) {
  __shared__ float wss[4];
  const int t = threadIdx.x;
  const size_t row = blockIdx.x;
  const float* xr = x + row * 1024;

  float4 xv = *(const float4*)&xr[t * 4];
  float v[4] = {xv.x, xv.y, xv.z, xv.w};
  float ss = v[0]*v[0] + v[1]*v[1] + v[2]*v[2] + v[3]*v[3];
#pragma unroll
  for (int mm = 1; mm < 64; mm <<= 1) ss += __shfl_xor(ss, mm);
  if ((t & 63) == 0) wss[t >> 6] = ss;
  __syncthreads();
  ss = wss[0] + wss[1] + wss[2] + wss[3];
  float inv = 32.0f / sqrtf(fmaxf(ss, 1e-24f));  // sqrt(1024)=32

  float4 gv = *(const float4*)&gamma[t * 4];
  float gvv[4] = {gv.x, gv.y, gv.z, gv.w};
  bf16x4 outv;
#pragma unroll
  for (int i = 0; i < 4; ++i) outv[i] = (bf16)(v[i] * inv * gvv[i]);
  *(bf16x4*)&xn[row * 1024 + t * 4] = outv;
}

// ---------------------------------------------------------------------------
// Kernel 2: fp32 -> bf16 transpose (for B^T GEMM operand), 32x32 tiles
// ---------------------------------------------------------------------------
__global__ void transpose_f32_bf16(const float* __restrict__ in, bf16* __restrict__ out,
                                   int R, int C) {
  __shared__ bf16 tile[32][33];
  const int tx = threadIdx.x, ty = threadIdx.y;  // 32 x 8
  const int c0 = blockIdx.x * 32, r0 = blockIdx.y * 32;
#pragma unroll
  for (int i = 0; i < 32; i += 8)
    tile[ty + i][tx] = (bf16)in[(size_t)(r0 + ty + i) * C + c0 + tx];
  __syncthreads();
#pragma unroll
  for (int i = 0; i < 32; i += 8)
    out[(size_t)(c0 + ty + i) * R + r0 + tx] = tile[tx][ty + i];
}

// Wg [1024,16] -> rows 3072..3087 of BtAug [3200,1024]. Tiny (16K elements).
__global__ __launch_bounds__(256) void wg_transpose(const float* __restrict__ Wg,
                                                    bf16* __restrict__ BtAug) {
  int idx = blockIdx.x * 256 + threadIdx.x;   // [0, 16384)
  int n = idx >> 10, k = idx & 1023;
  BtAug[(size_t)(3072 + n) * 1024 + k] = (bf16)Wg[(size_t)k * 16 + n];
}

// ---------------------------------------------------------------------------
// Kernel 3 (QKV GEMM): 256x256, BK=64, 128 KB LDS dbuf -- R2 "v2" schedule,
// REVERTED VERBATIM (best measured: 71.0 us; v6's B-direct regressed to 112:
// 16-row-scatter register loads amplify L2 transactions and sit un-hidden in
// the tile's serial chain. DMA-staged B with counted vmcnt is superior.)
//   ph0: read ALL B (regs, whole tile) + A chunk0 | ph p: A chunk p only
//   stage spread: ph0 b0,b1 | ph1 b2,b3,a0 | ph2 a1,a2 | ph3 a3
//   waits: vmcnt(4)/(6)/(7)/(3); never vmcnt(0) in the loop; raw s_barrier.
// ---------------------------------------------------------------------------
template <typename OutT>
__global__ __launch_bounds__(512, 2) void gemm_bt_256(
    const bf16* __restrict__ A, const bf16* __restrict__ Bt,
    OutT* __restrict__ C, int M, int N, int K) {
  extern __shared__ bf16 lds[];
  bf16* A0 = lds;               // [256][64]
  bf16* B0 = lds + 16384;
  bf16* A1 = lds + 32768;
  bf16* B1 = lds + 49152;

  const int t = threadIdx.x;
  const int w = t >> 6, lane = t & 63;
  const int wm = w >> 2, wn = w & 3;
  const int col0 = lane & 15, quad = lane >> 4;
  const int s_sub = lane >> 3;                    // row within wave's 8-row span
  const int sswz = (((lane & 7) ^ s_sub) << 3);   // pre-swizzled src 16B chunk

  // XCD-aware bijective swizzle (requires nwg % 8 == 0; 416 is)
  int nwg = gridDim.x * gridDim.y;
  int bid = blockIdx.y * gridDim.x + blockIdx.x;
  int swz = bid;
  if ((nwg & 7) == 0) swz = (bid & 7) * (nwg >> 3) + (bid >> 3);
  const int n0 = (swz % gridDim.x) * 256;
  const int m0 = (swz / gridDim.x) * 256;

  const bf16* Abase = A + (size_t)m0 * (size_t)K;

  auto stageA = [&](int ks, int c, bf16* dstA) {
    // chunk c covers rows {c*32..+31} (waves 0-3) u {128+c*32..+31} (waves 4-7)
    int rb = (w < 4) ? (c * 32 + w * 8) : (128 + c * 32 + (w - 4) * 8);
    g2lds16(Abase + (size_t)(rb + s_sub) * K + ks + sswz, dstA + rb * 64);
  };
  auto stageB = [&](int ks, int c, bf16* dstB) {
    int rb = c * 64 + w * 8;
    int gr = n0 + rb + s_sub;
    gr = (gr < N) ? gr : (N - 1);   // clamp: partial tile reads zero-pad row
    g2lds16(Bt + (size_t)gr * (size_t)K + ks + sswz, dstB + rb * 64);
  };

  f32x4 acc[8][4] = {};
  const int NT = K >> 6;   // K-tiles (16 for K=1024)
  const int NI = NT >> 1;

  // ---- prologue: tile 0's 8 loads; order ends a1,a2,a3 (ledger invariant)
#pragma unroll
  for (int c = 0; c < 4; ++c) stageB(0, c, B0);
  stageA(0, 0, A0);
  stageA(0, 1, A0); stageA(0, 2, A0); stageA(0, 3, A0);
  asm volatile("s_waitcnt vmcnt(3)" ::: "memory");
  __builtin_amdgcn_s_barrier();

  for (int i = 0; i < NI; ++i) {
#pragma unroll
    for (int h = 0; h < 2; ++h) {
      bf16* cA = h ? A1 : A0;   // compute buffers (tile 2i+h)
      bf16* cB = h ? B1 : B0;
      bf16* nA = h ? A0 : A1;   // stage targets (tile 2i+h+1)
      bf16* nB = h ? B0 : B1;
      int tn = 2 * i + h + 1;
      int kn = ((tn < NT) ? tn : 0) << 6;  // clamp: tail garbage never read

      // ---- phase 0: read ALL B (held across tile) + A chunk 0
      bf16x8 bv[4][2];
#pragma unroll
      for (int nj = 0; nj < 4; ++nj) {
        int br = wn * 64 + nj * 16 + col0;
#pragma unroll
        for (int ks = 0; ks < 2; ++ks)
          bv[nj][ks] = *(const bf16x8*)&cB[br * 64 + (((ks * 4 + quad) ^ (br & 7)) << 3)];
      }
      {
        bf16x8 af[2][2];
#pragma unroll
        for (int m2 = 0; m2 < 2; ++m2) {
          int ar = wm * 128 + m2 * 16 + col0;
#pragma unroll
          for (int ks = 0; ks < 2; ++ks)
            af[m2][ks] = *(const bf16x8*)&cA[ar * 64 + (((ks * 4 + quad) ^ (ar & 7)) << 3)];
        }
        stageB(kn, 0, nB); stageB(kn, 1, nB);
        __builtin_amdgcn_s_barrier();
        asm volatile("s_waitcnt lgkmcnt(0)" ::: "memory");
        __builtin_amdgcn_s_setprio(1);
#pragma unroll
        for (int ks = 0; ks < 2; ++ks)
#pragma unroll
          for (int m2 = 0; m2 < 2; ++m2)
#pragma unroll
            for (int nj = 0; nj < 4; ++nj)
              acc[m2][nj] = __builtin_amdgcn_mfma_f32_16x16x32_bf16(
                  af[m2][ks], bv[nj][ks], acc[m2][nj], 0, 0, 0);
        __builtin_amdgcn_s_setprio(0);
        asm volatile("s_waitcnt vmcnt(4)" ::: "memory");
        __builtin_amdgcn_s_barrier();
      }

      // ---- phases 1..3: read A chunk p only; B stays in registers
#pragma unroll
      for (int p = 1; p < 4; ++p) {
        bf16x8 af[2][2];
#pragma unroll
        for (int m2 = 0; m2 < 2; ++m2) {
          int ar = wm * 128 + (p * 2 + m2) * 16 + col0;
#pragma unroll
          for (int ks = 0; ks < 2; ++ks)
            af[m2][ks] = *(const bf16x8*)&cA[ar * 64 + (((ks * 4 + quad) ^ (ar & 7)) << 3)];
        }
        if (p == 1)      { stageB(kn, 2, nB); stageB(kn, 3, nB); stageA(kn, 0, nA); }
        else if (p == 2) { stageA(kn, 1, nA); stageA(kn, 2, nA); }
        else             { stageA(kn, 3, nA); }
        __builtin_amdgcn_s_barrier();
        asm volatile("s_waitcnt lgkmcnt(0)" ::: "memory");
        __builtin_amdgcn_s_setprio(1);
#pragma unroll
        for (int ks = 0; ks < 2; ++ks)
#pragma unroll
          for (int m2 = 0; m2 < 2; ++m2)
#pragma unroll
            for (int nj = 0; nj < 4; ++nj)
              acc[p * 2 + m2][nj] = __builtin_amdgcn_mfma_f32_16x16x32_bf16(
                  af[m2][ks], bv[nj][ks], acc[p * 2 + m2][nj], 0, 0, 0);
        __builtin_amdgcn_s_setprio(0);
        if (p == 1)      asm volatile("s_waitcnt vmcnt(6)" ::: "memory");
        else if (p == 2) asm volatile("s_waitcnt vmcnt(7)" ::: "memory");
        else             asm volatile("s_waitcnt vmcnt(3)" ::: "memory");
        __builtin_amdgcn_s_barrier();
      }
    }
  }
  // drain tail garbage stages before wave exit (LDS could be reassigned)
  asm volatile("s_waitcnt vmcnt(0)" ::: "memory");

  // epilogue: C/D layout col=lane&15, row=quad*4+r
#pragma unroll
  for (int mi = 0; mi < 8; ++mi)
#pragma unroll
    for (int nj = 0; nj < 4; ++nj) {
      int col = n0 + wn * 64 + nj * 16 + col0;
      if (col < N) {
        size_t base = (size_t)(m0 + wm * 128 + mi * 16 + quad * 4) * N + col;
#pragma unroll
        for (int r = 0; r < 4; ++r)
          C[base + (size_t)r * N] = (OutT)acc[mi][nj][r];
      }
    }
}

// ---------------------------------------------------------------------------
// Kernel 3c (out-GEMM): 256M x 128N tile, BK=64 -- v2 schedule ported.
// N=1024 -> grid 8x32 = 256 blocks = EXACTLY 1/CU (no tail imbalance, unlike
// the QKV grid's 416). LDS = (256+128)*64*2B * 2buf = 96 KB dynamic.
// Per wave (2Mx4N): 128 rows x 32 cols; acc[8][2]; bv[2][2] read at ph0.
// 6 staging loads/tile (b0,b1 + a0..a3). Ledger (per-thread FIFO; outstanding
// at T.ph0 entry = [a1,a2,a3] of T):
//   ph0: read B(all)+A0; issue b0',b1' ->5; vmcnt(4) drains a1 (T-1.ph2)
//   ph1: read A1;        issue a0'     ->5; vmcnt(4) drains a2 (T-1.ph3)
//   ph2: read A2;        issue a1'     ->5; vmcnt(4) drains a3 (T-1.ph3)
//   ph3: read A3;        issue a2',a3' ->6; vmcnt(3) drains b0',b1',a0'
// Every drained load >=2 phases old; never vmcnt(0) in loop. WAR safe: all
// stage targets are the other buffer, whose readers passed the prior tile's
// last barrier after lgkm-draining their reads (same proof as v2).
// ---------------------------------------------------------------------------
__global__ __launch_bounds__(512, 2) void gemm_out_256x128(
    const bf16* __restrict__ A, const bf16* __restrict__ Bt,
    float* __restrict__ C, int M, int N, int K) {
  extern __shared__ bf16 lds[];
  bf16* A0 = lds;               // [256][64] = 16384 elems
  bf16* B0 = lds + 16384;       // [128][64] =  8192 elems
  bf16* A1 = lds + 24576;
  bf16* B1 = lds + 40960;       // total 49152 elems = 96 KB

  const int t = threadIdx.x;
  const int w = t >> 6, lane = t & 63;
  const int wm = w >> 2, wn = w & 3;
  const int col0 = lane & 15, quad = lane >> 4;
  const int sswz = (((t & 7) ^ ((t >> 3) & 7)) << 3);  // pre-swizzled src chunk

  // XCD swizzle (256 % 8 == 0)
  int nwg = gridDim.x * gridDim.y;
  int bid = blockIdx.y * gridDim.x + blockIdx.x;
  int swz = (bid & 7) * (nwg >> 3) + (bid >> 3);
  const int n0 = (swz % gridDim.x) * 128;
  const int m0 = (swz / gridDim.x) * 256;

  const bf16* Abase = A + (size_t)m0 * (size_t)K;

  // A quarter c = 64 rows (512 thr x 16B = one quarter per call)
  auto stageA = [&](int ks, int c, bf16* dstA) {
    int row = c * 64 + (t >> 3);
    g2lds16(Abase + (size_t)row * K + ks + sswz, dstA + c * 4096 + w * 512);
  };
  // B half c = 64 rows
  auto stageB = [&](int ks, int c, bf16* dstB) {
    int gr = n0 + c * 64 + (t >> 3);
    g2lds16(Bt + (size_t)gr * (size_t)K + ks + sswz, dstB + c * 4096 + w * 512);
  };

  f32x4 acc[8][2] = {};
  const int NT = K >> 6;   // 16 for K=1024

  // prologue: b0,b1,a0 then a1,a2,a3 (ledger invariant: tail = a1,a2,a3)
  stageB(0, 0, B0); stageB(0, 1, B0);
  stageA(0, 0, A0);
  stageA(0, 1, A0); stageA(0, 2, A0); stageA(0, 3, A0);
  asm volatile("s_waitcnt vmcnt(3)" ::: "memory");  // b0,b1,a0 landed
  __builtin_amdgcn_s_barrier();

  for (int T = 0; T < NT; ++T) {
    bf16* cA = (T & 1) ? A1 : A0;
    bf16* cB = (T & 1) ? B1 : B0;
    bf16* nA = (T & 1) ? A0 : A1;
    bf16* nB = (T & 1) ? B0 : B1;
    const int tn = T + 1;
    const int kn = ((tn < NT) ? tn : 0) << 6;  // clamp: tail garbage never read

    bf16x8 bv[2][2];
#pragma unroll
    for (int p = 0; p < 4; ++p) {
      // pre-barrier reads (validated at previous phase's wait+barrier)
      if (p == 0) {
#pragma unroll
        for (int nj = 0; nj < 2; ++nj) {
          int br = wn * 32 + nj * 16 + col0;
#pragma unroll
          for (int ks = 0; ks < 2; ++ks)
            bv[nj][ks] = *(const bf16x8*)&cB[br * 64 + (((ks * 4 + quad) ^ (br & 7)) << 3)];
        }
      }
      bf16x8 af[2][2];
#pragma unroll
      for (int m2 = 0; m2 < 2; ++m2) {
        int ar = wm * 128 + (p * 2 + m2) * 16 + col0;
#pragma unroll
        for (int ks = 0; ks < 2; ++ks)
          af[m2][ks] = *(const bf16x8*)&cA[ar * 64 + (((ks * 4 + quad) ^ (ar & 7)) << 3)];
      }
      // staging issues
      if (p == 0)      { stageB(kn, 0, nB); stageB(kn, 1, nB); }
      else if (p == 1) { stageA(kn, 0, nA); }
      else if (p == 2) { stageA(kn, 1, nA); }
      else             { stageA(kn, 2, nA); stageA(kn, 3, nA); }
      __builtin_amdgcn_s_barrier();
      asm volatile("s_waitcnt lgkmcnt(0)" ::: "memory");
      __builtin_amdgcn_s_setprio(1);
#pragma unroll
      for (int ks = 0; ks < 2; ++ks)
#pragma unroll
        for (int m2 = 0; m2 < 2; ++m2)
#pragma unroll
          for (int nj = 0; nj < 2; ++nj)
            acc[p * 2 + m2][nj] = __builtin_amdgcn_mfma_f32_16x16x32_bf16(
                af[m2][ks], bv[nj][ks], acc[p * 2 + m2][nj], 0, 0, 0);
      __builtin_amdgcn_s_setprio(0);
      if (p == 3) asm volatile("s_waitcnt vmcnt(3)" ::: "memory");
      else        asm volatile("s_waitcnt vmcnt(4)" ::: "memory");
      __builtin_amdgcn_s_barrier();
    }
  }
  asm volatile("s_waitcnt vmcnt(0)" ::: "memory");  // drain tail garbage

  // epilogue: fp32 C
#pragma unroll
  for (int mi = 0; mi < 8; ++mi)
#pragma unroll
    for (int nj = 0; nj < 2; ++nj) {
      int col = n0 + wn * 32 + nj * 16 + col0;
      size_t base = (size_t)(m0 + wm * 128 + mi * 16 + quad * 4) * N + col;
#pragma unroll
      for (int r = 0; r < 4; ++r)
        C[base + (size_t)r * N] = acc[mi][nj][r];
    }
}

// ---------------------------------------------------------------------------
// Kernel 4 v5: sliding-window attention, swapped-operand form (unchanged).
// ---------------------------------------------------------------------------
#define NEG_BIG -1e30f
__global__ __launch_bounds__(256, 4) void attn_kernel(
    const bf16* __restrict__ qkv, const float* __restrict__ bg,
    bf16* __restrict__ attnO) {
  __shared__ bf16 lKV[320 * 64];   // 40 KB: K[320][64] ph1, Vt[64][320] ph2

  const int t = threadIdx.x;
  const int lane = t & 63;
  const int w = t >> 6;
  const int col0 = lane & 15, quad = lane >> 4;

  const int bid = blockIdx.x;
  const int blk = ((bid & 7) << 8) | (bid >> 3);   // XCD-chunked (2048 % 8 == 0)
  const int g = blk & 63;
  const int h = (blk >> 6) & 15;
  const int bb = blk >> 10;
  const int qs = g * 64;

  const size_t rs = 3200;
  const bf16* qbase = qkv + ((size_t)bb * 4096) * rs + h * 64;

  // ---- stage K[320][64] via async DMA (chunk-swizzled via source)
  {
    const int lr = t >> 3;                          // 0..31 (includes w*8)
    const int sswz = ((t & 7) ^ (lr & 7)) << 3;
#pragma unroll
    for (int c = 0; c < 10; ++c) {
      int j = qs - 256 + c * 32 + lr;
      j = (j < 0) ? 0 : j;                          // clamp: masked later
      g2lds16(qbase + 1024 + (size_t)j * rs + sswz, &lKV[c * 2048 + w * 512]);
    }
  }
  __builtin_amdgcn_sched_barrier(0);
  // ---- Q B-operand frags + gate logit direct from global (no LDS)
  const int ql = w * 16 + col0;                     // local query index
  const int srow = qs + ql;
  const bf16x8 bq0 = *(const bf16x8*)(qbase + (size_t)srow * rs + quad * 8);
  const bf16x8 bq1 = *(const bf16x8*)(qbase + (size_t)srow * rs + 32 + quad * 8);
  const float logit = (float)qkv[((size_t)bb * 4096 + srow) * rs + 3072 + h];
  asm volatile("s_waitcnt vmcnt(3)" ::: "memory");  // the 10 K DMAs done
  asm volatile("s_barrier" ::: "memory");

  // ---- QK^T swapped: z[kt] rows k = kt*16+quad*4+r, col q = col0
  f32x4 z[20];
#pragma unroll
  for (int kt = 0; kt < 20; ++kt) {
    const int kr = kt * 16 + col0;
    bf16x8 a0 = *(const bf16x8*)&lKV[kr * 64 + ((quad ^ (kr & 7)) << 3)];
    bf16x8 a1 = *(const bf16x8*)&lKV[kr * 64 + (((4 + quad) ^ (kr & 7)) << 3)];
    f32x4 zz = {};
    zz = __builtin_amdgcn_mfma_f32_16x16x32_bf16(a0, bq0, zz, 0, 0, 0);
    zz = __builtin_amdgcn_mfma_f32_16x16x32_bf16(a1, bq1, zz, 0, 0, 0);
    z[kt] = zz;
  }
  asm volatile("s_barrier" ::: "memory");           // all waves done reading K

  // ---- V -> Vt[64][320] overlay (key-major lanes, 2-way-free chunk swizzle)
  {
    const int jl = t & 31, dg = t >> 5;
#pragma unroll
    for (int cc = 0; cc < 10; ++cc) {
      int j = qs - 256 + cc * 32 + jl;
      j = (j < 0) ? 0 : j;                          // finite garbage; P=0 there
      bf16 tmp[8];
      *(uint4*)tmp = *(const uint4*)(qbase + 2048 + (size_t)j * rs + dg * 8);
      const int ck = cc * 4 + (jl >> 3);
      const int wi = jl & 7;
#pragma unroll
      for (int d2 = 0; d2 < 8; ++d2) {
        const int d = dg * 8 + d2;
        lKV[d * 320 + ((ck ^ (d & 7)) << 3) + wi] = tmp[d2];
      }
    }
  }

  // ---- softmax: lane owns 80 scores of ONE query; 2 shfl rounds per reduce
  float m = NEG_BIG;
#pragma unroll
  for (int kt = 0; kt < 20; ++kt)
#pragma unroll
    for (int r = 0; r < 4; ++r) {
      const int c = kt * 16 + quad * 4 + r;
      const bool valid = (c >= ql) && (c <= ql + 256) && (qs - 256 + c >= 0);
      const float sv = valid ? z[kt][r] * 0.125f : NEG_BIG;  // 1/sqrt(64)
      z[kt][r] = sv;
      m = fmaxf(m, sv);
    }
  m = fmaxf(m, __shfl_xor(m, 16));
  m = fmaxf(m, __shfl_xor(m, 32));
  float l = 0.f;
#pragma unroll
  for (int kt = 0; kt < 20; ++kt)
#pragma unroll
    for (int r = 0; r < 4; ++r) {
      const float p = __expf(z[kt][r] - m);
      z[kt][r] = p;
      l += p;
    }
  l += __shfl_xor(l, 16);
  l += __shfl_xor(l, 32);

  __syncthreads();                                  // Vt visible

  // ---- PV swapped: o[n] = O^T d-band; P transposed in-register.
  f32x4 o[4] = {};
  const int sl0 = col0 + ((quad & 1) << 5);
  const bool hi = quad >= 2;
#pragma unroll
  for (int kc = 0; kc < 10; ++kc) {
    uint32_t Pl0, Pl1, Ph0, Ph1;
    asm("v_cvt_pk_bf16_f32 %0, %1, %2" : "=v"(Pl0) : "v"(z[2*kc][0]),   "v"(z[2*kc][1]));
    asm("v_cvt_pk_bf16_f32 %0, %1, %2" : "=v"(Pl1) : "v"(z[2*kc][2]),   "v"(z[2*kc][3]));
    asm("v_cvt_pk_bf16_f32 %0, %1, %2" : "=v"(Ph0) : "v"(z[2*kc+1][0]), "v"(z[2*kc+1][1]));
    asm("v_cvt_pk_bf16_f32 %0, %1, %2" : "=v"(Ph1) : "v"(z[2*kc+1][2]), "v"(z[2*kc+1][3]));
    uint32_t w0l = __shfl((int)Pl0, sl0),      w0h = __shfl((int)Ph0, sl0);
    uint32_t w1l = __shfl((int)Pl1, sl0),      w1h = __shfl((int)Ph1, sl0);
    uint32_t w2l = __shfl((int)Pl0, sl0 + 16), w2h = __shfl((int)Ph0, sl0 + 16);
    uint32_t w3l = __shfl((int)Pl1, sl0 + 16), w3h = __shfl((int)Ph1, sl0 + 16);
    union { uint32_t u[4]; bf16x8 v; } pu;
    pu.u[0] = hi ? w0h : w0l;
    pu.u[1] = hi ? w1h : w1l;
    pu.u[2] = hi ? w2h : w2l;
    pu.u[3] = hi ? w3h : w3l;
#pragma unroll
    for (int n = 0; n < 4; ++n) {
      const int d = n * 16 + col0;
      bf16x8 av = *(const bf16x8*)&lKV[d * 320 + (((kc * 4 + quad) ^ (d & 7)) << 3)];
      o[n] = __builtin_amdgcn_mfma_f32_16x16x32_bf16(av, pu.v, o[n], 0, 0, 0);
    }
  }

  // ---- epilogue: one query per lane; o rows are d = n*16+quad*4+r
  const float gate = 1.f / (1.f + __expf(-(logit + bg[h])));
  const float scale = gate / l;
  bf16* obase = attnO + ((size_t)bb * 4096 + srow) * 1024 + h * 64;
#pragma unroll
  for (int n = 0; n < 4; ++n) {
    bf16x4 ov;
#pragma unroll
    for (int r = 0; r < 4; ++r) ov[r] = (bf16)(o[n][r] * scale);
    *(bf16x4*)&obase[n * 16 + quad * 4] = ov;
  }
}

// ---------------------------------------------------------------------------
extern "C" void kernel_launch(void* const* d_in, const int* in_sizes, int n_in,
                              void* d_out, int out_size, void* d_ws, size_t ws_size,
                              hipStream_t stream) {
  const float *x = nullptr, *gamma = nullptr, *Wqkv = nullptr,
              *Wg = nullptr, *bg = nullptr, *Wout = nullptr;
  for (int i = 0; i < n_in; ++i) {
    switch (in_sizes[i]) {
      case 8388608: x     = (const float*)d_in[i]; break;
      case 1024:    gamma = (const float*)d_in[i]; break;
      case 3145728: Wqkv  = (const float*)d_in[i]; break;
      case 16384:   Wg    = (const float*)d_in[i]; break;
      case 16:      bg    = (const float*)d_in[i]; break;
      case 1048576: Wout  = (const float*)d_in[i]; break;
    }
  }
  float* out = (float*)d_out;  // fp32 output

  // one-time: allow >64 KB dynamic LDS for both GEMMs
  static bool attr_done = false;
  if (!attr_done) {
    hipFuncSetAttribute(reinterpret_cast<const void*>(&gemm_bt_256<bf16>),
                        hipFuncAttributeMaxDynamicSharedMemorySize, 131072);
    hipFuncSetAttribute(reinterpret_cast<const void*>(&gemm_out_256x128),
                        hipFuncAttributeMaxDynamicSharedMemorySize, 98304);
    attr_done = true;
  }

  // BtAug = [WqkvT (3072 rows); WgT (16 rows); zero pad (112 rows)] x 1024
  char* ws = (char*)d_ws;
  bf16* qkv   = (bf16*)ws;  ws += (size_t)8192 * 3200 * 2;   // 52.4 MB (incl. gate logits)
  bf16* xn    = (bf16*)ws;                                    // 16 MB, dead after QKV GEMM
  bf16* attnO = (bf16*)ws;  ws += (size_t)8192 * 1024 * 2;   // aliases xn (stream-ordered)
  bf16* BtAug = (bf16*)ws;  ws += (size_t)3200 * 1024 * 2;   // 6.55 MB
  bf16* WoutT = (bf16*)ws;  ws += (size_t)1024 * 1024 * 2;   // total ~77.9 MB

  // zero the 112 pad rows of BtAug (re-poisoned to 0xAA before every call)
  hipMemsetAsync(BtAug + (size_t)3088 * 1024, 0, (size_t)112 * 1024 * 2, stream);

  rmsnorm_kernel<<<8192, 256, 0, stream>>>(x, gamma, xn);
  transpose_f32_bf16<<<dim3(3072 / 32, 1024 / 32), dim3(32, 8), 0, stream>>>(Wqkv, BtAug, 1024, 3072);
  wg_transpose<<<64, 256, 0, stream>>>(Wg, BtAug);
  transpose_f32_bf16<<<dim3(1024 / 32, 1024 / 32), dim3(32, 8), 0, stream>>>(Wout, WoutT, 1024, 1024);
  // QKV GEMM: 256^2 v2 (best measured 71 us), grid 13x32 = 416
  gemm_bt_256<bf16><<<dim3(13, 32), 512, 131072, stream>>>(xn, BtAug, qkv, 8192, 3200, 1024);
  attn_kernel<<<2048, 256, 0, stream>>>(qkv, bg, attnO);
  // out GEMM: 256x128 v2-port, grid 8x32 = 256 blocks = 1/CU (no tail)
  gemm_out_256x128<<<dim3(8, 32), 512, 98304, stream>>>(attnO, WoutT, out, 8192, 1024, 1024);
}

// Round 8
// 227.040 us; speedup vs baseline: 1.1914x; 1.0240x over previous
//
#include <hip/hip_runtime.h>
#include <hip/hip_bf16.h>
#include <stdint.h>

typedef __bf16 bf16;
typedef __bf16 bf16x4 __attribute__((ext_vector_type(4)));
typedef __bf16 bf16x8 __attribute__((ext_vector_type(8)));
typedef float f32x4 __attribute__((ext_vector_type(4)));

#define GLOBAL_AS __attribute__((address_space(1)))
#define LDS_AS __attribute__((address_space(3)))

__device__ __forceinline__ void g2lds16(const bf16* g, bf16* l) {
  // async global->LDS DMA, 16 B/lane; LDS dest = wave-uniform base + lane*16
  __builtin_amdgcn_global_load_lds((const GLOBAL_AS void*)g, (LDS_AS void*)l, 16, 0, 0);
}

// ---------------------------------------------------------------------------
// Kernel 1: pure streaming RMSNorm (F.normalize * sqrt(1024) * gamma).
// ---------------------------------------------------------------------------
__global__ __launch_bounds__(256) void rmsnorm_kernel(
    const float* __restrict__ x, const float* __restrict__ gamma,
    bf16* __restrict__ xn) {
  __shared__ float wss[4];
  const int t = threadIdx.x;
  const size_t row = blockIdx.x;
  const float* xr = x + row * 1024;

  float4 xv = *(const float4*)&xr[t * 4];
  float v[4] = {xv.x, xv.y, xv.z, xv.w};
  float ss = v[0]*v[0] + v[1]*v[1] + v[2]*v[2] + v[3]*v[3];
#pragma unroll
  for (int mm = 1; mm < 64; mm <<= 1) ss += __shfl_xor(ss, mm);
  if ((t & 63) == 0) wss[t >> 6] = ss;
  __syncthreads();
  ss = wss[0] + wss[1] + wss[2] + wss[3];
  float inv = 32.0f / sqrtf(fmaxf(ss, 1e-24f));  // sqrt(1024)=32

  float4 gv = *(const float4*)&gamma[t * 4];
  float gvv[4] = {gv.x, gv.y, gv.z, gv.w};
  bf16x4 outv;
#pragma unroll
  for (int i = 0; i < 4; ++i) outv[i] = (bf16)(v[i] * inv * gvv[i]);
  *(bf16x4*)&xn[row * 1024 + t * 4] = outv;
}

// ---------------------------------------------------------------------------
// Kernel 2 (fused weight prep): one launch replaces the 3 transpose kernels.
// Blocks [0,3072): Wqkv [1024,3072] -> BtAug rows 0..3071 (bf16, transposed)
// Blocks [3072,4096): Wout [1024,1024] -> WoutT (bf16, transposed)
// Blocks [4096,4160): Wg [1024,16] -> BtAug rows 3072..3087
// ---------------------------------------------------------------------------
__global__ void prep_weights(const float* __restrict__ Wqkv,
                             const float* __restrict__ Wout,
                             const float* __restrict__ Wg,
                             bf16* __restrict__ BtAug, bf16* __restrict__ WoutT) {
  __shared__ bf16 tile[32][33];
  const int bid = blockIdx.x;
  const int tx = threadIdx.x, ty = threadIdx.y;  // 32 x 8
  if (bid < 4096) {
    const float* in; bf16* out; int C, R, bx, by;
    if (bid < 3072) { in = Wqkv; out = BtAug; C = 3072; R = 1024; bx = bid % 96; by = bid / 96; }
    else { int b2 = bid - 3072; in = Wout; out = WoutT; C = 1024; R = 1024; bx = b2 & 31; by = b2 >> 5; }
    const int c0 = bx * 32, r0 = by * 32;
#pragma unroll
    for (int i = 0; i < 32; i += 8)
      tile[ty + i][tx] = (bf16)in[(size_t)(r0 + ty + i) * C + c0 + tx];
    __syncthreads();
#pragma unroll
    for (int i = 0; i < 32; i += 8)
      out[(size_t)(c0 + ty + i) * R + r0 + tx] = tile[tx][ty + i];
  } else {
    int idx = (bid - 4096) * 256 + ty * 32 + tx;  // [0, 16384)
    int n = idx >> 10, k = idx & 1023;
    BtAug[(size_t)(3072 + n) * 1024 + k] = (bf16)Wg[(size_t)k * 16 + n];
  }
}

// ---------------------------------------------------------------------------
// Kernel 3 (QKV GEMM): 256x256, BK=64, 128 KB LDS dbuf -- v2 schedule,
// unchanged (best measured 71-72 us).
//   ph0: read ALL B (regs, whole tile) + A chunk0 | ph p: A chunk p only
//   stage spread: ph0 b0,b1 | ph1 b2,b3,a0 | ph2 a1,a2 | ph3 a3
//   waits: vmcnt(4)/(6)/(7)/(3); never vmcnt(0) in the loop; raw s_barrier.
// A chunks are SPLIT ({c*32..+31} u {128+c*32..+31}) so chunk c == phase c.
// ---------------------------------------------------------------------------
template <typename OutT>
__global__ __launch_bounds__(512, 2) void gemm_bt_256(
    const bf16* __restrict__ A, const bf16* __restrict__ Bt,
    OutT* __restrict__ C, int M, int N, int K) {
  extern __shared__ bf16 lds[];
  bf16* A0 = lds;               // [256][64]
  bf16* B0 = lds + 16384;
  bf16* A1 = lds + 32768;
  bf16* B1 = lds + 49152;

  const int t = threadIdx.x;
  const int w = t >> 6, lane = t & 63;
  const int wm = w >> 2, wn = w & 3;
  const int col0 = lane & 15, quad = lane >> 4;
  const int s_sub = lane >> 3;                    // row within wave's 8-row span
  const int sswz = (((lane & 7) ^ s_sub) << 3);   // pre-swizzled src 16B chunk

  // XCD-aware bijective swizzle (requires nwg % 8 == 0; 416 is)
  int nwg = gridDim.x * gridDim.y;
  int bid = blockIdx.y * gridDim.x + blockIdx.x;
  int swz = bid;
  if ((nwg & 7) == 0) swz = (bid & 7) * (nwg >> 3) + (bid >> 3);
  const int n0 = (swz % gridDim.x) * 256;
  const int m0 = (swz / gridDim.x) * 256;

  const bf16* Abase = A + (size_t)m0 * (size_t)K;

  auto stageA = [&](int ks, int c, bf16* dstA) {
    // chunk c covers rows {c*32..+31} (waves 0-3) u {128+c*32..+31} (waves 4-7)
    int rb = (w < 4) ? (c * 32 + w * 8) : (128 + c * 32 + (w - 4) * 8);
    g2lds16(Abase + (size_t)(rb + s_sub) * K + ks + sswz, dstA + rb * 64);
  };
  auto stageB = [&](int ks, int c, bf16* dstB) {
    int rb = c * 64 + w * 8;
    int gr = n0 + rb + s_sub;
    gr = (gr < N) ? gr : (N - 1);   // clamp: partial tile reads zero-pad row
    g2lds16(Bt + (size_t)gr * (size_t)K + ks + sswz, dstB + rb * 64);
  };

  f32x4 acc[8][4] = {};
  const int NT = K >> 6;   // K-tiles (16 for K=1024)
  const int NI = NT >> 1;

  // ---- prologue: tile 0's 8 loads; order ends a1,a2,a3 (ledger invariant)
#pragma unroll
  for (int c = 0; c < 4; ++c) stageB(0, c, B0);
  stageA(0, 0, A0);
  stageA(0, 1, A0); stageA(0, 2, A0); stageA(0, 3, A0);
  asm volatile("s_waitcnt vmcnt(3)" ::: "memory");
  __builtin_amdgcn_s_barrier();

  for (int i = 0; i < NI; ++i) {
#pragma unroll
    for (int h = 0; h < 2; ++h) {
      bf16* cA = h ? A1 : A0;   // compute buffers (tile 2i+h)
      bf16* cB = h ? B1 : B0;
      bf16* nA = h ? A0 : A1;   // stage targets (tile 2i+h+1)
      bf16* nB = h ? B0 : B1;
      int tn = 2 * i + h + 1;
      int kn = ((tn < NT) ? tn : 0) << 6;  // clamp: tail garbage never read

      // ---- phase 0: read ALL B (held across tile) + A chunk 0
      bf16x8 bv[4][2];
#pragma unroll
      for (int nj = 0; nj < 4; ++nj) {
        int br = wn * 64 + nj * 16 + col0;
#pragma unroll
        for (int ks = 0; ks < 2; ++ks)
          bv[nj][ks] = *(const bf16x8*)&cB[br * 64 + (((ks * 4 + quad) ^ (br & 7)) << 3)];
      }
      {
        bf16x8 af[2][2];
#pragma unroll
        for (int m2 = 0; m2 < 2; ++m2) {
          int ar = wm * 128 + m2 * 16 + col0;
#pragma unroll
          for (int ks = 0; ks < 2; ++ks)
            af[m2][ks] = *(const bf16x8*)&cA[ar * 64 + (((ks * 4 + quad) ^ (ar & 7)) << 3)];
        }
        stageB(kn, 0, nB); stageB(kn, 1, nB);
        __builtin_amdgcn_s_barrier();
        asm volatile("s_waitcnt lgkmcnt(0)" ::: "memory");
        __builtin_amdgcn_s_setprio(1);
#pragma unroll
        for (int ks = 0; ks < 2; ++ks)
#pragma unroll
          for (int m2 = 0; m2 < 2; ++m2)
#pragma unroll
            for (int nj = 0; nj < 4; ++nj)
              acc[m2][nj] = __builtin_amdgcn_mfma_f32_16x16x32_bf16(
                  af[m2][ks], bv[nj][ks], acc[m2][nj], 0, 0, 0);
        __builtin_amdgcn_s_setprio(0);
        asm volatile("s_waitcnt vmcnt(4)" ::: "memory");
        __builtin_amdgcn_s_barrier();
      }

      // ---- phases 1..3: read A chunk p only; B stays in registers
#pragma unroll
      for (int p = 1; p < 4; ++p) {
        bf16x8 af[2][2];
#pragma unroll
        for (int m2 = 0; m2 < 2; ++m2) {
          int ar = wm * 128 + (p * 2 + m2) * 16 + col0;
#pragma unroll
          for (int ks = 0; ks < 2; ++ks)
            af[m2][ks] = *(const bf16x8*)&cA[ar * 64 + (((ks * 4 + quad) ^ (ar & 7)) << 3)];
        }
        if (p == 1)      { stageB(kn, 2, nB); stageB(kn, 3, nB); stageA(kn, 0, nA); }
        else if (p == 2) { stageA(kn, 1, nA); stageA(kn, 2, nA); }
        else             { stageA(kn, 3, nA); }
        __builtin_amdgcn_s_barrier();
        asm volatile("s_waitcnt lgkmcnt(0)" ::: "memory");
        __builtin_amdgcn_s_setprio(1);
#pragma unroll
        for (int ks = 0; ks < 2; ++ks)
#pragma unroll
          for (int m2 = 0; m2 < 2; ++m2)
#pragma unroll
            for (int nj = 0; nj < 4; ++nj)
              acc[p * 2 + m2][nj] = __builtin_amdgcn_mfma_f32_16x16x32_bf16(
                  af[m2][ks], bv[nj][ks], acc[p * 2 + m2][nj], 0, 0, 0);
        __builtin_amdgcn_s_setprio(0);
        if (p == 1)      asm volatile("s_waitcnt vmcnt(6)" ::: "memory");
        else if (p == 2) asm volatile("s_waitcnt vmcnt(7)" ::: "memory");
        else             asm volatile("s_waitcnt vmcnt(3)" ::: "memory");
        __builtin_amdgcn_s_barrier();
      }
    }
  }
  // drain tail garbage stages before wave exit (LDS could be reassigned)
  asm volatile("s_waitcnt vmcnt(0)" ::: "memory");

  // epilogue: C/D layout col=lane&15, row=quad*4+r
#pragma unroll
  for (int mi = 0; mi < 8; ++mi)
#pragma unroll
    for (int nj = 0; nj < 4; ++nj) {
      int col = n0 + wn * 64 + nj * 16 + col0;
      if (col < N) {
        size_t base = (size_t)(m0 + wm * 128 + mi * 16 + quad * 4) * N + col;
#pragma unroll
        for (int r = 0; r < 4; ++r)
          C[base + (size_t)r * N] = (OutT)acc[mi][nj][r];
      }
    }
}

// ---------------------------------------------------------------------------
// Kernel 3c (out-GEMM): 256M x 128N, BK=64, 96 KB LDS dbuf. R8 FIX: R7 used
// LINEAR A chunks (c*64..+63) while phase p reads rows {p*32}u{128+p*32} --
// ph0's wm=1 reads hit chunk a2 before its counted drain (race masked only by
// in-order DMA timing). Now A uses v2's SPLIT chunks (chunk c == phase c).
// Ledger (per-thread FIFO; 6 loads/tile b0,b1,a0..a3; issue for T+1:
//   ph0: b0',b1' | ph1: a0' | ph2: a1',a2' | ph3: a3'):
//   entry T.ph0: Q=[a1,a2,a3]. ph0 +2 ->5, W vmcnt(4) drains a1 (T-1.ph2)
//   ph1 +1 ->5, W vmcnt(4) drains a2 (T-1.ph2, 3 phases old)
//   ph2 +2 ->6, W vmcnt(5) drains a3 (T-1.ph3)
//   ph3 +1 ->6, W vmcnt(3) drains b0',b1',a0' (T+1.ph0 needs) -> invariant
// Every drain >=2 phases old; never vmcnt(0) in loop. N=1024 exact: no clamp.
// ---------------------------------------------------------------------------
__global__ __launch_bounds__(512, 2) void gemm_out_256x128(
    const bf16* __restrict__ A, const bf16* __restrict__ Bt,
    float* __restrict__ C, int M, int N, int K) {
  extern __shared__ bf16 lds[];
  bf16* A0 = lds;               // [256][64] = 16384 elems
  bf16* B0 = lds + 16384;       // [128][64] =  8192 elems
  bf16* A1 = lds + 24576;
  bf16* B1 = lds + 40960;       // total 49152 elems = 96 KB

  const int t = threadIdx.x;
  const int w = t >> 6, lane = t & 63;
  const int wm = w >> 2, wn = w & 3;                // wm 0-1 (128 rows), wn 0-3 (32 cols)
  const int col0 = lane & 15, quad = lane >> 4;
  const int s_sub = lane >> 3;
  const int sswz = (((lane & 7) ^ s_sub) << 3);     // pre-swizzled src 16B chunk

  // XCD swizzle (256 % 8 == 0)
  int nwg = gridDim.x * gridDim.y;
  int bid = blockIdx.y * gridDim.x + blockIdx.x;
  int swz = (bid & 7) * (nwg >> 3) + (bid >> 3);
  const int n0 = (swz % gridDim.x) * 128;
  const int m0 = (swz / gridDim.x) * 256;

  const bf16* Abase = A + (size_t)m0 * (size_t)K;

  // A chunk c covers rows {c*32..+31} (waves 0-3) u {128+c*32..+31} (waves 4-7)
  auto stageA = [&](int ks, int c, bf16* dstA) {
    int rb = (w < 4) ? (c * 32 + w * 8) : (128 + c * 32 + (w - 4) * 8);
    g2lds16(Abase + (size_t)(rb + s_sub) * K + ks + sswz, dstA + rb * 64);
  };
  // B chunk c covers rows c*64..+63
  auto stageB = [&](int ks, int c, bf16* dstB) {
    int rb = c * 64 + w * 8;
    g2lds16(Bt + (size_t)(n0 + rb + s_sub) * K + ks + sswz, dstB + rb * 64);
  };

  f32x4 acc[8][2] = {};
  const int NT = K >> 6;   // 16 for K=1024

  // prologue: b0,b1,a0 then a1,a2,a3 (ledger invariant: tail = a1,a2,a3)
  stageB(0, 0, B0); stageB(0, 1, B0);
  stageA(0, 0, A0);
  stageA(0, 1, A0); stageA(0, 2, A0); stageA(0, 3, A0);
  asm volatile("s_waitcnt vmcnt(3)" ::: "memory");  // b0,b1,a0 landed
  __builtin_amdgcn_s_barrier();

  for (int T = 0; T < NT; ++T) {
    bf16* cA = (T & 1) ? A1 : A0;
    bf16* cB = (T & 1) ? B1 : B0;
    bf16* nA = (T & 1) ? A0 : A1;
    bf16* nB = (T & 1) ? B0 : B1;
    const int tn = T + 1;
    const int kn = ((tn < NT) ? tn : 0) << 6;  // clamp: tail garbage never read

    bf16x8 bv[2][2];
#pragma unroll
    for (int p = 0; p < 4; ++p) {
      // pre-barrier reads (validated at previous phase's wait+barrier)
      if (p == 0) {
#pragma unroll
        for (int nj = 0; nj < 2; ++nj) {
          int br = wn * 32 + nj * 16 + col0;
#pragma unroll
          for (int ks = 0; ks < 2; ++ks)
            bv[nj][ks] = *(const bf16x8*)&cB[br * 64 + (((ks * 4 + quad) ^ (br & 7)) << 3)];
        }
      }
      bf16x8 af[2][2];
#pragma unroll
      for (int m2 = 0; m2 < 2; ++m2) {
        int ar = wm * 128 + (p * 2 + m2) * 16 + col0;   // in split-chunk p
#pragma unroll
        for (int ks = 0; ks < 2; ++ks)
          af[m2][ks] = *(const bf16x8*)&cA[ar * 64 + (((ks * 4 + quad) ^ (ar & 7)) << 3)];
      }
      // staging issues for tile T+1
      if (p == 0)      { stageB(kn, 0, nB); stageB(kn, 1, nB); }
      else if (p == 1) { stageA(kn, 0, nA); }
      else if (p == 2) { stageA(kn, 1, nA); stageA(kn, 2, nA); }
      else             { stageA(kn, 3, nA); }
      __builtin_amdgcn_s_barrier();
      asm volatile("s_waitcnt lgkmcnt(0)" ::: "memory");
      __builtin_amdgcn_s_setprio(1);
#pragma unroll
      for (int ks = 0; ks < 2; ++ks)
#pragma unroll
        for (int m2 = 0; m2 < 2; ++m2)
#pragma unroll
          for (int nj = 0; nj < 2; ++nj)
            acc[p * 2 + m2][nj] = __builtin_amdgcn_mfma_f32_16x16x32_bf16(
                af[m2][ks], bv[nj][ks], acc[p * 2 + m2][nj], 0, 0, 0);
      __builtin_amdgcn_s_setprio(0);
      if (p == 0)      asm volatile("s_waitcnt vmcnt(4)" ::: "memory");
      else if (p == 1) asm volatile("s_waitcnt vmcnt(4)" ::: "memory");
      else if (p == 2) asm volatile("s_waitcnt vmcnt(5)" ::: "memory");
      else             asm volatile("s_waitcnt vmcnt(3)" ::: "memory");
      __builtin_amdgcn_s_barrier();
    }
  }
  asm volatile("s_waitcnt vmcnt(0)" ::: "memory");  // drain tail garbage

  // epilogue: fp32 C
#pragma unroll
  for (int mi = 0; mi < 8; ++mi)
#pragma unroll
    for (int nj = 0; nj < 2; ++nj) {
      int col = n0 + wn * 32 + nj * 16 + col0;
      size_t base = (size_t)(m0 + wm * 128 + mi * 16 + quad * 4) * N + col;
#pragma unroll
      for (int r = 0; r < 4; ++r)
        C[base + (size_t)r * N] = acc[mi][nj][r];
    }
}

// ---------------------------------------------------------------------------
// Kernel 4 v5: sliding-window attention, swapped-operand form (unchanged).
// ---------------------------------------------------------------------------
#define NEG_BIG -1e30f
__global__ __launch_bounds__(256, 4) void attn_kernel(
    const bf16* __restrict__ qkv, const float* __restrict__ bg,
    bf16* __restrict__ attnO) {
  __shared__ bf16 lKV[320 * 64];   // 40 KB: K[320][64] ph1, Vt[64][320] ph2

  const int t = threadIdx.x;
  const int lane = t & 63;
  const int w = t >> 6;
  const int col0 = lane & 15, quad = lane >> 4;

  const int bid = blockIdx.x;
  const int blk = ((bid & 7) << 8) | (bid >> 3);   // XCD-chunked (2048 % 8 == 0)
  const int g = blk & 63;
  const int h = (blk >> 6) & 15;
  const int bb = blk >> 10;
  const int qs = g * 64;

  const size_t rs = 3200;
  const bf16* qbase = qkv + ((size_t)bb * 4096) * rs + h * 64;

  // ---- stage K[320][64] via async DMA (chunk-swizzled via source)
  {
    const int lr = t >> 3;                          // 0..31 (includes w*8)
    const int sswz = ((t & 7) ^ (lr & 7)) << 3;
#pragma unroll
    for (int c = 0; c < 10; ++c) {
      int j = qs - 256 + c * 32 + lr;
      j = (j < 0) ? 0 : j;                          // clamp: masked later
      g2lds16(qbase + 1024 + (size_t)j * rs + sswz, &lKV[c * 2048 + w * 512]);
    }
  }
  __builtin_amdgcn_sched_barrier(0);
  // ---- Q B-operand frags + gate logit direct from global (no LDS)
  const int ql = w * 16 + col0;                     // local query index
  const int srow = qs + ql;
  const bf16x8 bq0 = *(const bf16x8*)(qbase + (size_t)srow * rs + quad * 8);
  const bf16x8 bq1 = *(const bf16x8*)(qbase + (size_t)srow * rs + 32 + quad * 8);
  const float logit = (float)qkv[((size_t)bb * 4096 + srow) * rs + 3072 + h];
  asm volatile("s_waitcnt vmcnt(3)" ::: "memory");  // the 10 K DMAs done
  asm volatile("s_barrier" ::: "memory");

  // ---- QK^T swapped: z[kt] rows k = kt*16+quad*4+r, col q = col0
  f32x4 z[20];
#pragma unroll
  for (int kt = 0; kt < 20; ++kt) {
    const int kr = kt * 16 + col0;
    bf16x8 a0 = *(const bf16x8*)&lKV[kr * 64 + ((quad ^ (kr & 7)) << 3)];
    bf16x8 a1 = *(const bf16x8*)&lKV[kr * 64 + (((4 + quad) ^ (kr & 7)) << 3)];
    f32x4 zz = {};
    zz = __builtin_amdgcn_mfma_f32_16x16x32_bf16(a0, bq0, zz, 0, 0, 0);
    zz = __builtin_amdgcn_mfma_f32_16x16x32_bf16(a1, bq1, zz, 0, 0, 0);
    z[kt] = zz;
  }
  asm volatile("s_barrier" ::: "memory");           // all waves done reading K

  // ---- V -> Vt[64][320] overlay (key-major lanes, 2-way-free chunk swizzle)
  {
    const int jl = t & 31, dg = t >> 5;
#pragma unroll
    for (int cc = 0; cc < 10; ++cc) {
      int j = qs - 256 + cc * 32 + jl;
      j = (j < 0) ? 0 : j;                          // finite garbage; P=0 there
      bf16 tmp[8];
      *(uint4*)tmp = *(const uint4*)(qbase + 2048 + (size_t)j * rs + dg * 8);
      const int ck = cc * 4 + (jl >> 3);
      const int wi = jl & 7;
#pragma unroll
      for (int d2 = 0; d2 < 8; ++d2) {
        const int d = dg * 8 + d2;
        lKV[d * 320 + ((ck ^ (d & 7)) << 3) + wi] = tmp[d2];
      }
    }
  }

  // ---- softmax: lane owns 80 scores of ONE query; 2 shfl rounds per reduce
  float m = NEG_BIG;
#pragma unroll
  for (int kt = 0; kt < 20; ++kt)
#pragma unroll
    for (int r = 0; r < 4; ++r) {
      const int c = kt * 16 + quad * 4 + r;
      const bool valid = (c >= ql) && (c <= ql + 256) && (qs - 256 + c >= 0);
      const float sv = valid ? z[kt][r] * 0.125f : NEG_BIG;  // 1/sqrt(64)
      z[kt][r] = sv;
      m = fmaxf(m, sv);
    }
  m = fmaxf(m, __shfl_xor(m, 16));
  m = fmaxf(m, __shfl_xor(m, 32));
  float l = 0.f;
#pragma unroll
  for (int kt = 0; kt < 20; ++kt)
#pragma unroll
    for (int r = 0; r < 4; ++r) {
      const float p = __expf(z[kt][r] - m);
      z[kt][r] = p;
      l += p;
    }
  l += __shfl_xor(l, 16);
  l += __shfl_xor(l, 32);

  __syncthreads();                                  // Vt visible

  // ---- PV swapped: o[n] = O^T d-band; P transposed in-register.
  f32x4 o[4] = {};
  const int sl0 = col0 + ((quad & 1) << 5);
  const bool hi = quad >= 2;
#pragma unroll
  for (int kc = 0; kc < 10; ++kc) {
    uint32_t Pl0, Pl1, Ph0, Ph1;
    asm("v_cvt_pk_bf16_f32 %0, %1, %2" : "=v"(Pl0) : "v"(z[2*kc][0]),   "v"(z[2*kc][1]));
    asm("v_cvt_pk_bf16_f32 %0, %1, %2" : "=v"(Pl1) : "v"(z[2*kc][2]),   "v"(z[2*kc][3]));
    asm("v_cvt_pk_bf16_f32 %0, %1, %2" : "=v"(Ph0) : "v"(z[2*kc+1][0]), "v"(z[2*kc+1][1]));
    asm("v_cvt_pk_bf16_f32 %0, %1, %2" : "=v"(Ph1) : "v"(z[2*kc+1][2]), "v"(z[2*kc+1][3]));
    uint32_t w0l = __shfl((int)Pl0, sl0),      w0h = __shfl((int)Ph0, sl0);
    uint32_t w1l = __shfl((int)Pl1, sl0),      w1h = __shfl((int)Ph1, sl0);
    uint32_t w2l = __shfl((int)Pl0, sl0 + 16), w2h = __shfl((int)Ph0, sl0 + 16);
    uint32_t w3l = __shfl((int)Pl1, sl0 + 16), w3h = __shfl((int)Ph1, sl0 + 16);
    union { uint32_t u[4]; bf16x8 v; } pu;
    pu.u[0] = hi ? w0h : w0l;
    pu.u[1] = hi ? w1h : w1l;
    pu.u[2] = hi ? w2h : w2l;
    pu.u[3] = hi ? w3h : w3l;
#pragma unroll
    for (int n = 0; n < 4; ++n) {
      const int d = n * 16 + col0;
      bf16x8 av = *(const bf16x8*)&lKV[d * 320 + (((kc * 4 + quad) ^ (d & 7)) << 3)];
      o[n] = __builtin_amdgcn_mfma_f32_16x16x32_bf16(av, pu.v, o[n], 0, 0, 0);
    }
  }

  // ---- epilogue: one query per lane; o rows are d = n*16+quad*4+r
  const float gate = 1.f / (1.f + __expf(-(logit + bg[h])));
  const float scale = gate / l;
  bf16* obase = attnO + ((size_t)bb * 4096 + srow) * 1024 + h * 64;
#pragma unroll
  for (int n = 0; n < 4; ++n) {
    bf16x4 ov;
#pragma unroll
    for (int r = 0; r < 4; ++r) ov[r] = (bf16)(o[n][r] * scale);
    *(bf16x4*)&obase[n * 16 + quad * 4] = ov;
  }
}

// ---------------------------------------------------------------------------
extern "C" void kernel_launch(void* const* d_in, const int* in_sizes, int n_in,
                              void* d_out, int out_size, void* d_ws, size_t ws_size,
                              hipStream_t stream) {
  const float *x = nullptr, *gamma = nullptr, *Wqkv = nullptr,
              *Wg = nullptr, *bg = nullptr, *Wout = nullptr;
  for (int i = 0; i < n_in; ++i) {
    switch (in_sizes[i]) {
      case 8388608: x     = (const float*)d_in[i]; break;
      case 1024:    gamma = (const float*)d_in[i]; break;
      case 3145728: Wqkv  = (const float*)d_in[i]; break;
      case 16384:   Wg    = (const float*)d_in[i]; break;
      case 16:      bg    = (const float*)d_in[i]; break;
      case 1048576: Wout  = (const float*)d_in[i]; break;
    }
  }
  float* out = (float*)d_out;  // fp32 output

  // one-time: allow >64 KB dynamic LDS for both GEMMs
  static bool attr_done = false;
  if (!attr_done) {
    hipFuncSetAttribute(reinterpret_cast<const void*>(&gemm_bt_256<bf16>),
                        hipFuncAttributeMaxDynamicSharedMemorySize, 131072);
    hipFuncSetAttribute(reinterpret_cast<const void*>(&gemm_out_256x128),
                        hipFuncAttributeMaxDynamicSharedMemorySize, 98304);
    attr_done = true;
  }

  // BtAug = [WqkvT (3072 rows); WgT (16 rows); zero pad (112 rows)] x 1024
  char* ws = (char*)d_ws;
  bf16* qkv   = (bf16*)ws;  ws += (size_t)8192 * 3200 * 2;   // 52.4 MB (incl. gate logits)
  bf16* xn    = (bf16*)ws;                                    // 16 MB, dead after QKV GEMM
  bf16* attnO = (bf16*)ws;  ws += (size_t)8192 * 1024 * 2;   // aliases xn (stream-ordered)
  bf16* BtAug = (bf16*)ws;  ws += (size_t)3200 * 1024 * 2;   // 6.55 MB
  bf16* WoutT = (bf16*)ws;  ws += (size_t)1024 * 1024 * 2;   // total ~77.9 MB

  // zero the 112 pad rows of BtAug (re-poisoned to 0xAA before every call)
  hipMemsetAsync(BtAug + (size_t)3088 * 1024, 0, (size_t)112 * 1024 * 2, stream);

  rmsnorm_kernel<<<8192, 256, 0, stream>>>(x, gamma, xn);
  // fused weight prep: Wqkv-T (3072 blocks) + Wout-T (1024) + Wg-T (64)
  prep_weights<<<4160, dim3(32, 8), 0, stream>>>(Wqkv, Wout, Wg, BtAug, WoutT);
  // QKV GEMM: 256^2 v2 (best measured 71 us), grid 13x32 = 416
  gemm_bt_256<bf16><<<dim3(13, 32), 512, 131072, stream>>>(xn, BtAug, qkv, 8192, 3200, 1024);
  attn_kernel<<<2048, 256, 0, stream>>>(qkv, bg, attnO);
  // out GEMM: 256x128 split-chunk (race-fixed), grid 8x32 = 256 blocks = 1/CU
  gemm_out_256x128<<<dim3(8, 32), 512, 98304, stream>>>(attnO, WoutT, out, 8192, 1024, 1024);
}

// Round 11
// 213.198 us; speedup vs baseline: 1.2688x; 1.0649x over previous
//
#include <hip/hip_runtime.h>
#include <hip/hip_bf16.h>
#include <stdint.h>

typedef __bf16 bf16;
typedef __bf16 bf16x4 __attribute__((ext_vector_type(4)));
typedef __bf16 bf16x8 __attribute__((ext_vector_type(8)));
typedef float f32x4 __attribute__((ext_vector_type(4)));
typedef unsigned int uint32x2 __attribute__((ext_vector_type(2)));

#define GLOBAL_AS __attribute__((address_space(1)))
#define LDS_AS __attribute__((address_space(3)))

__device__ __forceinline__ void g2lds16(const bf16* g, bf16* l) {
  // async global->LDS DMA, 16 B/lane; LDS dest = wave-uniform base + lane*16
  __builtin_amdgcn_global_load_lds((const GLOBAL_AS void*)g, (LDS_AS void*)l, 16, 0, 0);
}

// ---------------------------------------------------------------------------
// Kernel 1 (fused pre-pass): rmsnorm + all weight prep + pad-zero, ONE launch.
// Blocks [0,8192):        rmsnorm row bid (x -> xn bf16)
// Blocks [8192,11264):    Wqkv [1024,3072] -> BtAug rows 0..3071 (transposed)
// Blocks [11264,12288):   Wout [1024,1024] -> WoutT (transposed)
// Blocks [12288,12352):   Wg [1024,16] -> BtAug rows 3072..3087
// Blocks [12352,12408):   zero BtAug pad rows 3088..3199 (replaces memset)
// ---------------------------------------------------------------------------
__global__ __launch_bounds__(256) void prep_all(
    const float* __restrict__ x, const float* __restrict__ gamma,
    const float* __restrict__ Wqkv, const float* __restrict__ Wout,
    const float* __restrict__ Wg,
    bf16* __restrict__ xn, bf16* __restrict__ BtAug, bf16* __restrict__ WoutT) {
  __shared__ bf16 tile[32][33];
  __shared__ float wss[4];
  const int bid = blockIdx.x;
  const int t = threadIdx.x;

  if (bid < 8192) {
    // ---- RMSNorm (F.normalize * sqrt(1024) * gamma)
    const float* xr = x + (size_t)bid * 1024;
    float4 xv = *(const float4*)&xr[t * 4];
    float v[4] = {xv.x, xv.y, xv.z, xv.w};
    float ss = v[0]*v[0] + v[1]*v[1] + v[2]*v[2] + v[3]*v[3];
#pragma unroll
    for (int mm = 1; mm < 64; mm <<= 1) ss += __shfl_xor(ss, mm);
    if ((t & 63) == 0) wss[t >> 6] = ss;
    __syncthreads();
    ss = wss[0] + wss[1] + wss[2] + wss[3];
    float inv = 32.0f / sqrtf(fmaxf(ss, 1e-24f));  // sqrt(1024)=32
    float4 gv = *(const float4*)&gamma[t * 4];
    float gvv[4] = {gv.x, gv.y, gv.z, gv.w};
    bf16x4 outv;
#pragma unroll
    for (int i = 0; i < 4; ++i) outv[i] = (bf16)(v[i] * inv * gvv[i]);
    *(bf16x4*)&xn[(size_t)bid * 1024 + t * 4] = outv;
  } else if (bid < 12288) {
    // ---- fp32 -> bf16 32x32 tiled transpose (Wqkv / Wout)
    int b = bid - 8192;
    const float* in; bf16* out; int C, R, bx, by;
    if (b < 3072) { in = Wqkv; out = BtAug; C = 3072; R = 1024; bx = b % 96; by = b / 96; }
    else { int b2 = b - 3072; in = Wout; out = WoutT; C = 1024; R = 1024; bx = b2 & 31; by = b2 >> 5; }
    const int tx = t & 31, ty = t >> 5;  // 32 x 8
    const int c0 = bx * 32, r0 = by * 32;
#pragma unroll
    for (int i = 0; i < 32; i += 8)
      tile[ty + i][tx] = (bf16)in[(size_t)(r0 + ty + i) * C + c0 + tx];
    __syncthreads();
#pragma unroll
    for (int i = 0; i < 32; i += 8)
      out[(size_t)(c0 + ty + i) * R + r0 + tx] = tile[tx][ty + i];
  } else if (bid < 12352) {
    // ---- Wg transpose (tiny)
    int idx = (bid - 12288) * 256 + t;   // [0, 16384)
    int n = idx >> 10, k = idx & 1023;
    BtAug[(size_t)(3072 + n) * 1024 + k] = (bf16)Wg[(size_t)k * 16 + n];
  } else {
    // ---- zero the 112 pad rows (re-poisoned to 0xAA before every call)
    int idx = (bid - 12352) * 256 + t;   // [0, 14336) ; 14336*8 = 112*1024 exact
    uint4 z = {0, 0, 0, 0};
    *(uint4*)&BtAug[(size_t)3088 * 1024 + (size_t)idx * 8] = z;
  }
}

// ---------------------------------------------------------------------------
// Kernel 3 (QKV GEMM): 256x256, BK=64, 128 KB LDS dbuf -- v2 schedule,
// unchanged (best measured 71-72 us; per-tile eff is m201-class, residue is
// the unfixable 416/512 grid tail).
// ---------------------------------------------------------------------------
template <typename OutT>
__global__ __launch_bounds__(512, 2) void gemm_bt_256(
    const bf16* __restrict__ A, const bf16* __restrict__ Bt,
    OutT* __restrict__ C, int M, int N, int K) {
  extern __shared__ bf16 lds[];
  bf16* A0 = lds;               // [256][64]
  bf16* B0 = lds + 16384;
  bf16* A1 = lds + 32768;
  bf16* B1 = lds + 49152;

  const int t = threadIdx.x;
  const int w = t >> 6, lane = t & 63;
  const int wm = w >> 2, wn = w & 3;
  const int col0 = lane & 15, quad = lane >> 4;
  const int s_sub = lane >> 3;                    // row within wave's 8-row span
  const int sswz = (((lane & 7) ^ s_sub) << 3);   // pre-swizzled src 16B chunk

  int nwg = gridDim.x * gridDim.y;
  int bid = blockIdx.y * gridDim.x + blockIdx.x;
  int swz = bid;
  if ((nwg & 7) == 0) swz = (bid & 7) * (nwg >> 3) + (bid >> 3);
  const int n0 = (swz % gridDim.x) * 256;
  const int m0 = (swz / gridDim.x) * 256;

  const bf16* Abase = A + (size_t)m0 * (size_t)K;

  auto stageA = [&](int ks, int c, bf16* dstA) {
    int rb = (w < 4) ? (c * 32 + w * 8) : (128 + c * 32 + (w - 4) * 8);
    g2lds16(Abase + (size_t)(rb + s_sub) * K + ks + sswz, dstA + rb * 64);
  };
  auto stageB = [&](int ks, int c, bf16* dstB) {
    int rb = c * 64 + w * 8;
    int gr = n0 + rb + s_sub;
    gr = (gr < N) ? gr : (N - 1);   // clamp: partial tile reads zero-pad row
    g2lds16(Bt + (size_t)gr * (size_t)K + ks + sswz, dstB + rb * 64);
  };

  f32x4 acc[8][4] = {};
  const int NT = K >> 6;
  const int NI = NT >> 1;

#pragma unroll
  for (int c = 0; c < 4; ++c) stageB(0, c, B0);
  stageA(0, 0, A0);
  stageA(0, 1, A0); stageA(0, 2, A0); stageA(0, 3, A0);
  asm volatile("s_waitcnt vmcnt(3)" ::: "memory");
  __builtin_amdgcn_s_barrier();

  for (int i = 0; i < NI; ++i) {
#pragma unroll
    for (int h = 0; h < 2; ++h) {
      bf16* cA = h ? A1 : A0;
      bf16* cB = h ? B1 : B0;
      bf16* nA = h ? A0 : A1;
      bf16* nB = h ? B0 : B1;
      int tn = 2 * i + h + 1;
      int kn = ((tn < NT) ? tn : 0) << 6;

      bf16x8 bv[4][2];
#pragma unroll
      for (int nj = 0; nj < 4; ++nj) {
        int br = wn * 64 + nj * 16 + col0;
#pragma unroll
        for (int ks = 0; ks < 2; ++ks)
          bv[nj][ks] = *(const bf16x8*)&cB[br * 64 + (((ks * 4 + quad) ^ (br & 7)) << 3)];
      }
      {
        bf16x8 af[2][2];
#pragma unroll
        for (int m2 = 0; m2 < 2; ++m2) {
          int ar = wm * 128 + m2 * 16 + col0;
#pragma unroll
          for (int ks = 0; ks < 2; ++ks)
            af[m2][ks] = *(const bf16x8*)&cA[ar * 64 + (((ks * 4 + quad) ^ (ar & 7)) << 3)];
        }
        stageB(kn, 0, nB); stageB(kn, 1, nB);
        __builtin_amdgcn_s_barrier();
        asm volatile("s_waitcnt lgkmcnt(0)" ::: "memory");
        __builtin_amdgcn_s_setprio(1);
#pragma unroll
        for (int ks = 0; ks < 2; ++ks)
#pragma unroll
          for (int m2 = 0; m2 < 2; ++m2)
#pragma unroll
            for (int nj = 0; nj < 4; ++nj)
              acc[m2][nj] = __builtin_amdgcn_mfma_f32_16x16x32_bf16(
                  af[m2][ks], bv[nj][ks], acc[m2][nj], 0, 0, 0);
        __builtin_amdgcn_s_setprio(0);
        asm volatile("s_waitcnt vmcnt(4)" ::: "memory");
        __builtin_amdgcn_s_barrier();
      }

#pragma unroll
      for (int p = 1; p < 4; ++p) {
        bf16x8 af[2][2];
#pragma unroll
        for (int m2 = 0; m2 < 2; ++m2) {
          int ar = wm * 128 + (p * 2 + m2) * 16 + col0;
#pragma unroll
          for (int ks = 0; ks < 2; ++ks)
            af[m2][ks] = *(const bf16x8*)&cA[ar * 64 + (((ks * 4 + quad) ^ (ar & 7)) << 3)];
        }
        if (p == 1)      { stageB(kn, 2, nB); stageB(kn, 3, nB); stageA(kn, 0, nA); }
        else if (p == 2) { stageA(kn, 1, nA); stageA(kn, 2, nA); }
        else             { stageA(kn, 3, nA); }
        __builtin_amdgcn_s_barrier();
        asm volatile("s_waitcnt lgkmcnt(0)" ::: "memory");
        __builtin_amdgcn_s_setprio(1);
#pragma unroll
        for (int ks = 0; ks < 2; ++ks)
#pragma unroll
          for (int m2 = 0; m2 < 2; ++m2)
#pragma unroll
            for (int nj = 0; nj < 4; ++nj)
              acc[p * 2 + m2][nj] = __builtin_amdgcn_mfma_f32_16x16x32_bf16(
                  af[m2][ks], bv[nj][ks], acc[p * 2 + m2][nj], 0, 0, 0);
        __builtin_amdgcn_s_setprio(0);
        if (p == 1)      asm volatile("s_waitcnt vmcnt(6)" ::: "memory");
        else if (p == 2) asm volatile("s_waitcnt vmcnt(7)" ::: "memory");
        else             asm volatile("s_waitcnt vmcnt(3)" ::: "memory");
        __builtin_amdgcn_s_barrier();
      }
    }
  }
  asm volatile("s_waitcnt vmcnt(0)" ::: "memory");

#pragma unroll
  for (int mi = 0; mi < 8; ++mi)
#pragma unroll
    for (int nj = 0; nj < 4; ++nj) {
      int col = n0 + wn * 64 + nj * 16 + col0;
      if (col < N) {
        size_t base = (size_t)(m0 + wm * 128 + mi * 16 + quad * 4) * N + col;
#pragma unroll
        for (int r = 0; r < 4; ++r)
          C[base + (size_t)r * N] = (OutT)acc[mi][nj][r];
      }
    }
}

// ---------------------------------------------------------------------------
// Kernel 3c (out-GEMM): 256M x 128N, BK=64, split-chunk staging (R8, proven).
// ---------------------------------------------------------------------------
__global__ __launch_bounds__(512, 2) void gemm_out_256x128(
    const bf16* __restrict__ A, const bf16* __restrict__ Bt,
    float* __restrict__ C, int M, int N, int K) {
  extern __shared__ bf16 lds[];
  bf16* A0 = lds;               // [256][64]
  bf16* B0 = lds + 16384;       // [128][64]
  bf16* A1 = lds + 24576;
  bf16* B1 = lds + 40960;       // 96 KB

  const int t = threadIdx.x;
  const int w = t >> 6, lane = t & 63;
  const int wm = w >> 2, wn = w & 3;
  const int col0 = lane & 15, quad = lane >> 4;
  const int s_sub = lane >> 3;
  const int sswz = (((lane & 7) ^ s_sub) << 3);

  int nwg = gridDim.x * gridDim.y;
  int bid = blockIdx.y * gridDim.x + blockIdx.x;
  int swz = (bid & 7) * (nwg >> 3) + (bid >> 3);
  const int n0 = (swz % gridDim.x) * 128;
  const int m0 = (swz / gridDim.x) * 256;

  const bf16* Abase = A + (size_t)m0 * (size_t)K;

  auto stageA = [&](int ks, int c, bf16* dstA) {
    int rb = (w < 4) ? (c * 32 + w * 8) : (128 + c * 32 + (w - 4) * 8);
    g2lds16(Abase + (size_t)(rb + s_sub) * K + ks + sswz, dstA + rb * 64);
  };
  auto stageB = [&](int ks, int c, bf16* dstB) {
    int rb = c * 64 + w * 8;
    g2lds16(Bt + (size_t)(n0 + rb + s_sub) * K + ks + sswz, dstB + rb * 64);
  };

  f32x4 acc[8][2] = {};
  const int NT = K >> 6;

  stageB(0, 0, B0); stageB(0, 1, B0);
  stageA(0, 0, A0);
  stageA(0, 1, A0); stageA(0, 2, A0); stageA(0, 3, A0);
  asm volatile("s_waitcnt vmcnt(3)" ::: "memory");
  __builtin_amdgcn_s_barrier();

  for (int T = 0; T < NT; ++T) {
    bf16* cA = (T & 1) ? A1 : A0;
    bf16* cB = (T & 1) ? B1 : B0;
    bf16* nA = (T & 1) ? A0 : A1;
    bf16* nB = (T & 1) ? B0 : B1;
    const int tn = T + 1;
    const int kn = ((tn < NT) ? tn : 0) << 6;

    bf16x8 bv[2][2];
#pragma unroll
    for (int p = 0; p < 4; ++p) {
      if (p == 0) {
#pragma unroll
        for (int nj = 0; nj < 2; ++nj) {
          int br = wn * 32 + nj * 16 + col0;
#pragma unroll
          for (int ks = 0; ks < 2; ++ks)
            bv[nj][ks] = *(const bf16x8*)&cB[br * 64 + (((ks * 4 + quad) ^ (br & 7)) << 3)];
        }
      }
      bf16x8 af[2][2];
#pragma unroll
      for (int m2 = 0; m2 < 2; ++m2) {
        int ar = wm * 128 + (p * 2 + m2) * 16 + col0;
#pragma unroll
        for (int ks = 0; ks < 2; ++ks)
          af[m2][ks] = *(const bf16x8*)&cA[ar * 64 + (((ks * 4 + quad) ^ (ar & 7)) << 3)];
      }
      if (p == 0)      { stageB(kn, 0, nB); stageB(kn, 1, nB); }
      else if (p == 1) { stageA(kn, 0, nA); }
      else if (p == 2) { stageA(kn, 1, nA); stageA(kn, 2, nA); }
      else             { stageA(kn, 3, nA); }
      __builtin_amdgcn_s_barrier();
      asm volatile("s_waitcnt lgkmcnt(0)" ::: "memory");
      __builtin_amdgcn_s_setprio(1);
#pragma unroll
      for (int ks = 0; ks < 2; ++ks)
#pragma unroll
        for (int m2 = 0; m2 < 2; ++m2)
#pragma unroll
          for (int nj = 0; nj < 2; ++nj)
            acc[p * 2 + m2][nj] = __builtin_amdgcn_mfma_f32_16x16x32_bf16(
                af[m2][ks], bv[nj][ks], acc[p * 2 + m2][nj], 0, 0, 0);
      __builtin_amdgcn_s_setprio(0);
      if (p == 0)      asm volatile("s_waitcnt vmcnt(4)" ::: "memory");
      else if (p == 1) asm volatile("s_waitcnt vmcnt(4)" ::: "memory");
      else if (p == 2) asm volatile("s_waitcnt vmcnt(5)" ::: "memory");
      else             asm volatile("s_waitcnt vmcnt(3)" ::: "memory");
      __builtin_amdgcn_s_barrier();
    }
  }
  asm volatile("s_waitcnt vmcnt(0)" ::: "memory");

#pragma unroll
  for (int mi = 0; mi < 8; ++mi)
#pragma unroll
    for (int nj = 0; nj < 2; ++nj) {
      int col = n0 + wn * 32 + nj * 16 + col0;
      size_t base = (size_t)(m0 + wm * 128 + mi * 16 + quad * 4) * N + col;
#pragma unroll
      for (int r = 0; r < 4; ++r)
        C[base + (size_t)r * N] = acc[mi][nj][r];
    }
}

// ---------------------------------------------------------------------------
// Kernel 4 v6b: attn with tr-read V path, ADDRESSING FIXED (R10 post-mortem).
// ds_read_b64_tr_b16 semantics (m156/m162 reconstruction): the 16-lane
// group's addresses define its 128 B window -- lane l CONTRIBUTES the 8 B
// slot at its own address and RECEIVES column (l&15) of the assembled 4x16
// row-major bf16 tile. So per-lane addr = subtile_base + (l&15)*8 BYTES
// (R10's bug: used (l&15)*2 -- lanes read overlapping garbage).
//   trlane = quad*128 (group window) + col0*8 (lane slot), bytes.
//   tr result elem j = tile[j*16 + col0] = V[key 8*quad + (h?4:0) + j][d].
// V staged via global_load_lds DMA into linear 4(key)x16(d) subtiles;
// thread t: subtile T=t>>3 (qq=T&3, dgh=T>>2; kq=2qq+(dgh>>2)),
// row j=(t&7)>>1, dhalf=t&1 -> src = V[32c+4kq+j][16(dgh&3)+8dhalf .. +8].
// rule #18: lgkmcnt(0) + sched_barrier(0) between tr-reads and MFMAs.
// ---------------------------------------------------------------------------
#define NEG_BIG -1e30f
__global__ __launch_bounds__(256, 4) void attn_kernel(
    const bf16* __restrict__ qkv, const float* __restrict__ bg,
    bf16* __restrict__ attnO) {
  __shared__ bf16 lKV[320 * 64];   // 40 KB: K[320][64] ph1; V subtiles ph2

  const int t = threadIdx.x;
  const int lane = t & 63;
  const int w = t >> 6;
  const int col0 = lane & 15, quad = lane >> 4;

  const int bid = blockIdx.x;
  const int blk = ((bid & 7) << 8) | (bid >> 3);   // XCD-chunked (2048 % 8 == 0)
  const int g = blk & 63;
  const int h = (blk >> 6) & 15;
  const int bb = blk >> 10;
  const int qs = g * 64;

  const size_t rs = 3200;
  const bf16* qbase = qkv + ((size_t)bb * 4096) * rs + h * 64;

  // ---- stage K[320][64] via async DMA (chunk-swizzled via source)
  {
    const int lr = t >> 3;                          // 0..31 (includes w*8)
    const int sswz = ((t & 7) ^ (lr & 7)) << 3;
#pragma unroll
    for (int c = 0; c < 10; ++c) {
      int j = qs - 256 + c * 32 + lr;
      j = (j < 0) ? 0 : j;                          // clamp: masked later
      g2lds16(qbase + 1024 + (size_t)j * rs + sswz, &lKV[c * 2048 + w * 512]);
    }
  }
  __builtin_amdgcn_sched_barrier(0);
  // ---- Q B-operand frags + gate logit direct from global (no LDS)
  const int ql = w * 16 + col0;                     // local query index
  const int srow = qs + ql;
  const bf16x8 bq0 = *(const bf16x8*)(qbase + (size_t)srow * rs + quad * 8);
  const bf16x8 bq1 = *(const bf16x8*)(qbase + (size_t)srow * rs + 32 + quad * 8);
  const float logit = (float)qkv[((size_t)bb * 4096 + srow) * rs + 3072 + h];
  asm volatile("s_waitcnt vmcnt(3)" ::: "memory");  // the 10 K DMAs done
  asm volatile("s_barrier" ::: "memory");

  // ---- QK^T swapped: z[kt] rows k = kt*16+quad*4+r, col q = col0
  f32x4 z[20];
#pragma unroll
  for (int kt = 0; kt < 20; ++kt) {
    const int kr = kt * 16 + col0;
    bf16x8 a0 = *(const bf16x8*)&lKV[kr * 64 + ((quad ^ (kr & 7)) << 3)];
    bf16x8 a1 = *(const bf16x8*)&lKV[kr * 64 + (((4 + quad) ^ (kr & 7)) << 3)];
    f32x4 zz = {};
    zz = __builtin_amdgcn_mfma_f32_16x16x32_bf16(a0, bq0, zz, 0, 0, 0);
    zz = __builtin_amdgcn_mfma_f32_16x16x32_bf16(a1, bq1, zz, 0, 0, 0);
    z[kt] = zz;
  }
  asm volatile("s_barrier" ::: "memory");           // all waves done reading K

  // ---- V -> LDS via DMA, 4x16 (key x d) subtiles; overlaps softmax below.
  {
    const int ti  = t >> 3;                         // subtile index 0..31
    const int qq  = ti & 3;
    const int dgh = ti >> 2;                        // 0..7
    const int kq  = 2 * qq + (dgh >> 2);
    const int dcol = (dgh & 3) * 16 + (t & 1) * 8;
    const int jrow = (t & 7) >> 1;
#pragma unroll
    for (int c = 0; c < 10; ++c) {
      int jg = qs - 256 + c * 32 + kq * 4 + jrow;
      jg = (jg < 0) ? 0 : jg;                       // finite garbage; P=0 there
      g2lds16(qbase + 2048 + (size_t)jg * rs + dcol, &lKV[c * 2048 + w * 512]);
    }
  }
  __builtin_amdgcn_sched_barrier(0);

  // ---- softmax: lane owns 80 scores of ONE query; 2 shfl rounds per reduce
  float m = NEG_BIG;
#pragma unroll
  for (int kt = 0; kt < 20; ++kt)
#pragma unroll
    for (int r = 0; r < 4; ++r) {
      const int c = kt * 16 + quad * 4 + r;
      const bool valid = (c >= ql) && (c <= ql + 256) && (qs - 256 + c >= 0);
      const float sv = valid ? z[kt][r] * 0.125f : NEG_BIG;  // 1/sqrt(64)
      z[kt][r] = sv;
      m = fmaxf(m, sv);
    }
  m = fmaxf(m, __shfl_xor(m, 16));
  m = fmaxf(m, __shfl_xor(m, 32));
  float l = 0.f;
#pragma unroll
  for (int kt = 0; kt < 20; ++kt)
#pragma unroll
    for (int r = 0; r < 4; ++r) {
      const float p = __expf(z[kt][r] - m);
      z[kt][r] = p;
      l += p;
    }
  l += __shfl_xor(l, 16);
  l += __shfl_xor(l, 32);

  __syncthreads();   // drains V DMAs (vmcnt0) + barrier: V visible to all

  // ---- PV swapped: o[n] = O^T d-band; P transposed in-register (v5 path).
  f32x4 o[4] = {};
  const int sl0 = col0 + ((quad & 1) << 5);
  const bool hi = quad >= 2;
  // FIXED per-lane tr-read offset: group window quad*128 B + lane slot col0*8 B
  const int trlane = quad * 128 + col0 * 8;
#pragma unroll
  for (int kc = 0; kc < 10; ++kc) {
    uint32_t Pl0, Pl1, Ph0, Ph1;
    asm("v_cvt_pk_bf16_f32 %0, %1, %2" : "=v"(Pl0) : "v"(z[2*kc][0]),   "v"(z[2*kc][1]));
    asm("v_cvt_pk_bf16_f32 %0, %1, %2" : "=v"(Pl1) : "v"(z[2*kc][2]),   "v"(z[2*kc][3]));
    asm("v_cvt_pk_bf16_f32 %0, %1, %2" : "=v"(Ph0) : "v"(z[2*kc+1][0]), "v"(z[2*kc+1][1]));
    asm("v_cvt_pk_bf16_f32 %0, %1, %2" : "=v"(Ph1) : "v"(z[2*kc+1][2]), "v"(z[2*kc+1][3]));
    uint32_t w0l = __shfl((int)Pl0, sl0),      w0h = __shfl((int)Ph0, sl0);
    uint32_t w1l = __shfl((int)Pl1, sl0),      w1h = __shfl((int)Ph1, sl0);
    uint32_t w2l = __shfl((int)Pl0, sl0 + 16), w2h = __shfl((int)Ph0, sl0 + 16);
    uint32_t w3l = __shfl((int)Pl1, sl0 + 16), w3h = __shfl((int)Ph1, sl0 + 16);
    union { uint32_t u[4]; bf16x8 v; } pu;
    pu.u[0] = hi ? w0h : w0l;
    pu.u[1] = hi ? w1h : w1l;
    pu.u[2] = hi ? w2h : w2l;
    pu.u[3] = hi ? w3h : w3l;

    // 8 tr-reads: V A-operand fragments for n=0..3 (h=0/1 key-halves).
    // subtile S = (h*4+n)*4 + quad -> keys [8*quad + 4h, +4), d [16n, +16)
    uint32x2 tr[4][2];
#pragma unroll
    for (int n = 0; n < 4; ++n) {
      int a0 = (kc * 2048 + n * 256) * 2 + trlane;        // h=0
      int a1 = (kc * 2048 + (4 + n) * 256) * 2 + trlane;  // h=1
      asm volatile("ds_read_b64_tr_b16 %0, %1" : "=&v"(tr[n][0]) : "v"(a0));
      asm volatile("ds_read_b64_tr_b16 %0, %1" : "=&v"(tr[n][1]) : "v"(a1));
    }
    asm volatile("s_waitcnt lgkmcnt(0)" ::: "memory");
    __builtin_amdgcn_sched_barrier(0);                    // rule #18
#pragma unroll
    for (int n = 0; n < 4; ++n) {
      union { uint32x2 u[2]; bf16x8 v; } av;
      av.u[0] = tr[n][0]; av.u[1] = tr[n][1];
      o[n] = __builtin_amdgcn_mfma_f32_16x16x32_bf16(av.v, pu.v, o[n], 0, 0, 0);
    }
  }

  // ---- epilogue: one query per lane; o rows are d = n*16+quad*4+r
  const float gate = 1.f / (1.f + __expf(-(logit + bg[h])));
  const float scale = gate / l;
  bf16* obase = attnO + ((size_t)bb * 4096 + srow) * 1024 + h * 64;
#pragma unroll
  for (int n = 0; n < 4; ++n) {
    bf16x4 ov;
#pragma unroll
    for (int r = 0; r < 4; ++r) ov[r] = (bf16)(o[n][r] * scale);
    *(bf16x4*)&obase[n * 16 + quad * 4] = ov;
  }
}

// ---------------------------------------------------------------------------
extern "C" void kernel_launch(void* const* d_in, const int* in_sizes, int n_in,
                              void* d_out, int out_size, void* d_ws, size_t ws_size,
                              hipStream_t stream) {
  const float *x = nullptr, *gamma = nullptr, *Wqkv = nullptr,
              *Wg = nullptr, *bg = nullptr, *Wout = nullptr;
  for (int i = 0; i < n_in; ++i) {
    switch (in_sizes[i]) {
      case 8388608: x     = (const float*)d_in[i]; break;
      case 1024:    gamma = (const float*)d_in[i]; break;
      case 3145728: Wqkv  = (const float*)d_in[i]; break;
      case 16384:   Wg    = (const float*)d_in[i]; break;
      case 16:      bg    = (const float*)d_in[i]; break;
      case 1048576: Wout  = (const float*)d_in[i]; break;
    }
  }
  float* out = (float*)d_out;  // fp32 output

  // one-time: allow >64 KB dynamic LDS for both GEMMs
  static bool attr_done = false;
  if (!attr_done) {
    hipFuncSetAttribute(reinterpret_cast<const void*>(&gemm_bt_256<bf16>),
                        hipFuncAttributeMaxDynamicSharedMemorySize, 131072);
    hipFuncSetAttribute(reinterpret_cast<const void*>(&gemm_out_256x128),
                        hipFuncAttributeMaxDynamicSharedMemorySize, 98304);
    attr_done = true;
  }

  // BtAug = [WqkvT (3072 rows); WgT (16 rows); zero pad (112 rows)] x 1024
  char* ws = (char*)d_ws;
  bf16* qkv   = (bf16*)ws;  ws += (size_t)8192 * 3200 * 2;   // 52.4 MB (incl. gate logits)
  bf16* xn    = (bf16*)ws;                                    // 16 MB, dead after QKV GEMM
  bf16* attnO = (bf16*)ws;  ws += (size_t)8192 * 1024 * 2;   // aliases xn (stream-ordered)
  bf16* BtAug = (bf16*)ws;  ws += (size_t)3200 * 1024 * 2;   // 6.55 MB
  bf16* WoutT = (bf16*)ws;  ws += (size_t)1024 * 1024 * 2;   // total ~77.9 MB

  // fused pre-pass: rmsnorm + Wqkv/Wout/Wg transposes + pad-zero (4 launches total)
  prep_all<<<12408, 256, 0, stream>>>(x, gamma, Wqkv, Wout, Wg, xn, BtAug, WoutT);
  // QKV GEMM: 256^2 v2 (best measured 71 us), grid 13x32 = 416
  gemm_bt_256<bf16><<<dim3(13, 32), 512, 131072, stream>>>(xn, BtAug, qkv, 8192, 3200, 1024);
  attn_kernel<<<2048, 256, 0, stream>>>(qkv, bg, attnO);
  // out GEMM: 256x128 split-chunk, grid 8x32 = 256 blocks = 1/CU (no tail)
  gemm_out_256x128<<<dim3(8, 32), 512, 98304, stream>>>(attnO, WoutT, out, 8192, 1024, 1024);
}